// Round 1
// baseline (5695.190 us; speedup 1.0000x reference)
//
#include <hip/hip_runtime.h>
#include <math.h>

// Problem constants
static constexpr int BB  = 256;   // batch
static constexpr int IH_ = 200;   // internal tokens
static constexpr int IL_ = 6;     // internal feature dim
static constexpr int LH_ = 100;   // leaf tokens
static constexpr int EE  = 256;   // embed dim
static constexpr int FFH_= 512;   // ff hidden
static constexpr int NL_ = 2;     // layers
static constexpr int GG  = 301;   // IH+LH+1
static constexpr int TPB = 4;     // tokens per block in tiled kernels
static constexpr int NT  = (GG + TPB - 1) / TPB; // 76

// ---------------- block reduction helpers (wave = 64) ----------------
__device__ __forceinline__ float waveReduceSum(float v) {
    for (int o = 32; o > 0; o >>= 1) v += __shfl_down(v, o, 64);
    return v;
}
__device__ __forceinline__ float waveReduceMax(float v) {
    for (int o = 32; o > 0; o >>= 1) v = fmaxf(v, __shfl_down(v, o, 64));
    return v;
}
__device__ __forceinline__ float blockReduceSum(float v, float* red) {
    int lane = threadIdx.x & 63;
    int w    = threadIdx.x >> 6;
    int nw   = (blockDim.x + 63) >> 6;
    v = waveReduceSum(v);
    if (lane == 0) red[w] = v;
    __syncthreads();
    if (threadIdx.x < 64) {
        float x = (lane < nw) ? red[lane] : 0.0f;
        x = waveReduceSum(x);
        if (lane == 0) red[0] = x;
    }
    __syncthreads();
    float r = red[0];
    __syncthreads();
    return r;
}
__device__ __forceinline__ float blockReduceMax(float v, float* red) {
    int lane = threadIdx.x & 63;
    int w    = threadIdx.x >> 6;
    int nw   = (blockDim.x + 63) >> 6;
    v = waveReduceMax(v);
    if (lane == 0) red[w] = v;
    __syncthreads();
    if (threadIdx.x < 64) {
        float x = (lane < nw) ? red[lane] : -INFINITY;
        x = waveReduceMax(x);
        if (lane == 0) red[0] = x;
    }
    __syncthreads();
    float r = red[0];
    __syncthreads();
    return r;
}

// ---------------- embed: 3 small MLPs -> h ----------------
__global__ __launch_bounds__(256) void embed_kernel(
    const float* __restrict__ obs,
    const float* __restrict__ wi1, const float* __restrict__ bi1,
    const float* __restrict__ wi2, const float* __restrict__ bi2,
    const float* __restrict__ wl1, const float* __restrict__ bl1,
    const float* __restrict__ wl2, const float* __restrict__ bl2,
    const float* __restrict__ wn1, const float* __restrict__ bn1,
    const float* __restrict__ wn2, const float* __restrict__ bn2,
    float* __restrict__ h)
{
    int bg = blockIdx.x;
    int g  = bg % GG;
    const float* x = obs + (size_t)bg * 9;
    const float *w1, *b1, *w2, *b2;
    int ind;
    if (g < IH_)            { w1 = wi1; b1 = bi1; w2 = wi2; b2 = bi2; ind = IL_; }
    else if (g < IH_ + LH_) { w1 = wl1; b1 = bl1; w2 = wl2; b2 = bl2; ind = 8;  }
    else                    { w1 = wn1; b1 = bn1; w2 = wn2; b2 = bn2; ind = 6;  }

    __shared__ float xs[8];
    __shared__ float hid[32];
    int t = threadIdx.x;
    if (t < ind) xs[t] = x[t];
    __syncthreads();
    if (t < 32) {
        float a = b1[t];
        for (int i = 0; i < ind; i++) a += xs[i] * w1[i * 32 + t];
        hid[t] = (a > 0.0f) ? a : 0.01f * a;   // leaky_relu 0.01
    }
    __syncthreads();
    float a = b2[t];
    #pragma unroll
    for (int j = 0; j < 32; j++) a += hid[j] * w2[j * EE + t];
    h[(size_t)bg * EE + t] = a;
}

// ---------------- K,V projection for 4 tokens/block ----------------
__global__ __launch_bounds__(256) void kv_kernel(
    const float* __restrict__ h, const float* __restrict__ wk,
    const float* __restrict__ wv, float* __restrict__ kb, float* __restrict__ vb)
{
    int b  = blockIdx.y;
    int i0 = blockIdx.x * TPB;
    int rows = min(TPB, GG - i0);
    int t = threadIdx.x;
    __shared__ float hs[TPB][EE];
    for (int r = 0; r < TPB; r++)
        hs[r][t] = (r < rows) ? h[((size_t)b * GG + i0 + r) * EE + t] : 0.0f;
    __syncthreads();

    float ka[TPB] = {0, 0, 0, 0}, va[TPB] = {0, 0, 0, 0};
    for (int kk = 0; kk < EE; kk++) {
        float wkv = wk[kk * EE + t];
        float wvv = wv[kk * EE + t];
        #pragma unroll
        for (int r = 0; r < TPB; r++) { ka[r] += hs[r][kk] * wkv; va[r] += hs[r][kk] * wvv; }
    }
    for (int r = 0; r < rows; r++) {
        kb[((size_t)b * GG + i0 + r) * EE + t] = ka[r];
        vb[((size_t)b * GG + i0 + r) * EE + t] = va[r];
    }
}

// ------- fused attention: q-proj, scores, softmax, PV, WO, residual, LN -------
__global__ __launch_bounds__(256) void attn_kernel(
    float* __restrict__ h, const float* __restrict__ kb, const float* __restrict__ vb,
    const float* __restrict__ wq, const float* __restrict__ wo,
    const float* __restrict__ obs)
{
    int b  = blockIdx.y;
    int i0 = blockIdx.x * TPB;
    int rows = min(TPB, GG - i0);
    int t = threadIdx.x;

    __shared__ float hs[TPB][EE];
    __shared__ float qs[TPB][EE];     // reused later for normalized PV output
    __shared__ float sc[TPB][GG + 3];
    __shared__ float red[8];
    __shared__ float invs[TPB];

    for (int r = 0; r < TPB; r++)
        hs[r][t] = (r < rows) ? h[((size_t)b * GG + i0 + r) * EE + t] : 0.0f;
    __syncthreads();

    // q = h @ wq   (thread = output channel)
    float qa[TPB] = {0, 0, 0, 0};
    for (int kk = 0; kk < EE; kk++) {
        float w = wq[kk * EE + t];
        #pragma unroll
        for (int r = 0; r < TPB; r++) qa[r] += hs[r][kk] * w;
    }
    for (int r = 0; r < TPB; r++) qs[r][t] = qa[r];
    __syncthreads();

    // scores: thread = key index j
    const float scale = 0.0625f;
    for (int j = t; j < GG; j += blockDim.x) {
        const float4* kr = reinterpret_cast<const float4*>(kb + ((size_t)b * GG + j) * EE);
        float d[TPB] = {0, 0, 0, 0};
        for (int kk = 0; kk < EE / 4; kk++) {
            float4 kvv = kr[kk];
            int base = kk * 4;
            #pragma unroll
            for (int r = 0; r < TPB; r++)
                d[r] += qs[r][base] * kvv.x + qs[r][base + 1] * kvv.y +
                        qs[r][base + 2] * kvv.z + qs[r][base + 3] * kvv.w;
        }
        float bias = (1.0f - obs[((size_t)b * GG + j) * 9 + 8]) * -1e9f;
        #pragma unroll
        for (int r = 0; r < TPB; r++) sc[r][j] = d[r] * scale + bias;
    }
    __syncthreads();

    // softmax per row
    for (int r = 0; r < rows; r++) {
        float lm = -INFINITY;
        for (int j = t; j < GG; j += blockDim.x) lm = fmaxf(lm, sc[r][j]);
        float bm = blockReduceMax(lm, red);
        float ls = 0.0f;
        for (int j = t; j < GG; j += blockDim.x) {
            float e = __expf(sc[r][j] - bm);
            sc[r][j] = e;
            ls += e;
        }
        float bs = blockReduceSum(ls, red);
        if (t == 0) invs[r] = 1.0f / bs;
    }
    __syncthreads();

    // PV: thread = output channel e
    float pv[TPB] = {0, 0, 0, 0};
    for (int j = 0; j < GG; j++) {
        float vv = vb[((size_t)b * GG + j) * EE + t];
        #pragma unroll
        for (int r = 0; r < TPB; r++) pv[r] += sc[r][j] * vv;
    }
    // store normalized attention output into qs (qs no longer needed)
    for (int r = 0; r < TPB; r++) qs[r][t] = pv[r] * invs[r];
    __syncthreads();

    // WO + residual + LN
    float out[TPB];
    for (int r = 0; r < TPB; r++) out[r] = hs[r][t];
    for (int kk = 0; kk < EE; kk++) {
        float w = wo[kk * EE + t];
        #pragma unroll
        for (int r = 0; r < TPB; r++) out[r] += qs[r][kk] * w;
    }
    for (int r = 0; r < rows; r++) {
        float s  = blockReduceSum(out[r], red);
        float s2 = blockReduceSum(out[r] * out[r], red);
        float mean = s * (1.0f / EE);
        float var  = s2 * (1.0f / EE) - mean * mean;
        float nv = (out[r] - mean) * rsqrtf(var + 1e-5f);
        h[((size_t)b * GG + i0 + r) * EE + t] = nv;
    }
}

// ------------- fused FF: relu(h@wf1+b1)@wf2+b2 + residual + LN -------------
__global__ __launch_bounds__(256) void ff_kernel(
    float* __restrict__ h,
    const float* __restrict__ wf1, const float* __restrict__ bf1,
    const float* __restrict__ wf2, const float* __restrict__ bf2)
{
    int b  = blockIdx.y;
    int i0 = blockIdx.x * TPB;
    int rows = min(TPB, GG - i0);
    int t = threadIdx.x;
    __shared__ float hs[TPB][EE];
    __shared__ float hid[TPB][FFH_];
    __shared__ float red[8];
    for (int r = 0; r < TPB; r++)
        hs[r][t] = (r < rows) ? h[((size_t)b * GG + i0 + r) * EE + t] : 0.0f;
    __syncthreads();

    float bb1 = bf1[t], bb2 = bf1[t + EE];
    float a1[TPB], a2[TPB];
    #pragma unroll
    for (int r = 0; r < TPB; r++) { a1[r] = bb1; a2[r] = bb2; }
    for (int kk = 0; kk < EE; kk++) {
        float w1 = wf1[kk * FFH_ + t];
        float w2 = wf1[kk * FFH_ + t + EE];
        #pragma unroll
        for (int r = 0; r < TPB; r++) {
            float x = hs[r][kk];
            a1[r] += x * w1;
            a2[r] += x * w2;
        }
    }
    #pragma unroll
    for (int r = 0; r < TPB; r++) {
        hid[r][t]      = fmaxf(a1[r], 0.0f);
        hid[r][t + EE] = fmaxf(a2[r], 0.0f);
    }
    __syncthreads();

    float b2v = bf2[t];
    float out[TPB];
    #pragma unroll
    for (int r = 0; r < TPB; r++) out[r] = hs[r][t] + b2v;
    for (int kk = 0; kk < FFH_; kk++) {
        float w = wf2[kk * EE + t];
        #pragma unroll
        for (int r = 0; r < TPB; r++) out[r] += hid[r][kk] * w;
    }
    for (int r = 0; r < rows; r++) {
        float s  = blockReduceSum(out[r], red);
        float s2 = blockReduceSum(out[r] * out[r], red);
        float mean = s * (1.0f / EE);
        float var  = s2 * (1.0f / EE) - mean * mean;
        float nv = (out[r] - mean) * rsqrtf(var + 1e-5f);
        h[((size_t)b * GG + i0 + r) * EE + t] = nv;
    }
}

// ------------- head part 1: graph embed -> fixed context -> u[b] -------------
// u[b][e'] = sum_e w_pn[e'][e] * fc[b][e]   (only first E cols of w_pn matter)
__global__ __launch_bounds__(256) void final1_kernel(
    const float* __restrict__ h, const float* __restrict__ obs,
    const float* __restrict__ w_fc, const float* __restrict__ w_pn,
    float* __restrict__ u)
{
    int b = blockIdx.x;
    int t = threadIdx.x;
    __shared__ float ges[EE];
    __shared__ float fcs[EE];

    float acc = 0.0f, vlen = 0.0f;
    for (int g = 0; g < GG; g++) {
        float m = obs[((size_t)b * GG + g) * 9 + 8];
        vlen += m;
        acc += h[((size_t)b * GG + g) * EE + t] * m;
    }
    ges[t] = acc / vlen;
    __syncthreads();

    float fc = 0.0f;
    for (int kk = 0; kk < EE; kk++) fc += ges[kk] * w_fc[kk * EE + t];
    fcs[t] = fc;
    __syncthreads();

    const float4* wp = reinterpret_cast<const float4*>(w_pn + (size_t)t * 3 * EE);
    float ua = 0.0f;
    for (int kk = 0; kk < EE / 4; kk++) {
        float4 w = wp[kk];
        ua += w.x * fcs[kk * 4] + w.y * fcs[kk * 4 + 1] +
              w.z * fcs[kk * 4 + 2] + w.w * fcs[kk * 4 + 3];
    }
    u[(size_t)b * EE + t] = ua;
}

// ------------- head part 2: compat -> tanh clip -> masked softmax -------------
__global__ __launch_bounds__(128) void final2_kernel(
    const float* __restrict__ h, const float* __restrict__ obs,
    const float* __restrict__ u, float* __restrict__ out)
{
    int b = blockIdx.x;
    int t = threadIdx.x;  // 128 threads
    __shared__ float us[EE];
    __shared__ float red[8];
    us[t]       = u[(size_t)b * EE + t];
    us[t + 128] = u[(size_t)b * EE + t + 128];
    __syncthreads();

    float logit = -INFINITY;
    float m = 0.0f;
    if (t < LH_) {
        int g = IH_ + t;
        m = obs[((size_t)b * GG + g) * 9 + 8];   // leaf_valid == full_mask there
        const float4* hr = reinterpret_cast<const float4*>(h + ((size_t)b * GG + g) * EE);
        float c = 0.0f;
        for (int kk = 0; kk < EE / 4; kk++) {
            float4 hv = hr[kk];
            c += hv.x * us[kk * 4] + hv.y * us[kk * 4 + 1] +
                 hv.z * us[kk * 4 + 2] + hv.w * us[kk * 4 + 3];
        }
        c *= m;            // trans = h * mask
        c *= 0.0625f;      // 1/sqrt(E)
        logit = tanhf(c) * 10.0f;
    }
    float bm = blockReduceMax(logit, red);
    float e  = (t < LH_) ? __expf(logit - bm) : 0.0f;
    float bs = blockReduceSum(e, red);
    float p  = e / bs;
    float masked = (t < LH_) ? (p * m + 1e-20f) : 0.0f;
    float bs2 = blockReduceSum(masked, red);
    if (t < LH_) out[(size_t)b * LH_ + t] = masked / bs2;
}

extern "C" void kernel_launch(void* const* d_in, const int* in_sizes, int n_in,
                              void* d_out, int out_size, void* d_ws, size_t ws_size,
                              hipStream_t stream) {
    const float* obs   = (const float*)d_in[0];
    const float* wi1   = (const float*)d_in[1];
    const float* bi1   = (const float*)d_in[2];
    const float* wi2   = (const float*)d_in[3];
    const float* bi2   = (const float*)d_in[4];
    const float* wl1   = (const float*)d_in[5];
    const float* bl1   = (const float*)d_in[6];
    const float* wl2   = (const float*)d_in[7];
    const float* bl2   = (const float*)d_in[8];
    const float* wn1   = (const float*)d_in[9];
    const float* bn1   = (const float*)d_in[10];
    const float* wn2   = (const float*)d_in[11];
    const float* bn2   = (const float*)d_in[12];
    const float* e_wq  = (const float*)d_in[13];
    const float* e_wk  = (const float*)d_in[14];
    const float* e_wv  = (const float*)d_in[15];
    const float* e_wo  = (const float*)d_in[16];
    const float* e_wf1 = (const float*)d_in[17];
    const float* e_bf1 = (const float*)d_in[18];
    const float* e_wf2 = (const float*)d_in[19];
    const float* e_bf2 = (const float*)d_in[20];
    const float* w_pn  = (const float*)d_in[21];
    const float* w_fc  = (const float*)d_in[22];
    float* outp = (float*)d_out;

    float* ws = (float*)d_ws;
    size_t H = (size_t)BB * GG * EE;
    float* h    = ws;
    float* kbuf = ws + H;
    float* vbuf = ws + 2 * H;
    float* ubuf = ws + 3 * H;

    embed_kernel<<<BB * GG, EE, 0, stream>>>(obs, wi1, bi1, wi2, bi2,
                                             wl1, bl1, wl2, bl2,
                                             wn1, bn1, wn2, bn2, h);
    for (int l = 0; l < NL_; l++) {
        const float* wq = e_wq + (size_t)l * EE * EE;
        const float* wk = e_wk + (size_t)l * EE * EE;
        const float* wv = e_wv + (size_t)l * EE * EE;
        const float* wo = e_wo + (size_t)l * EE * EE;
        const float* wf1 = e_wf1 + (size_t)l * EE * FFH_;
        const float* bf1 = e_bf1 + (size_t)l * FFH_;
        const float* wf2 = e_wf2 + (size_t)l * FFH_ * EE;
        const float* bf2 = e_bf2 + (size_t)l * EE;
        kv_kernel<<<dim3(NT, BB), EE, 0, stream>>>(h, wk, wv, kbuf, vbuf);
        attn_kernel<<<dim3(NT, BB), EE, 0, stream>>>(h, kbuf, vbuf, wq, wo, obs);
        ff_kernel<<<dim3(NT, BB), EE, 0, stream>>>(h, wf1, bf1, wf2, bf2);
    }
    final1_kernel<<<BB, EE, 0, stream>>>(h, obs, w_fc, w_pn, ubuf);
    final2_kernel<<<BB, 128, 0, stream>>>(h, obs, ubuf, outp);
}

// Round 2
// 2042.892 us; speedup vs baseline: 2.7878x; 2.7878x over previous
//
#include <hip/hip_runtime.h>
#include <math.h>

static constexpr int BB   = 256;   // batch
static constexpr int IHN  = 200;   // internal tokens
static constexpr int ILN  = 6;     // internal feature dim
static constexpr int LHN  = 100;   // leaf tokens
static constexpr int EE   = 256;   // embed dim
static constexpr int FFH  = 512;   // ff hidden
static constexpr int NL   = 2;     // layers
static constexpr int GG   = 301;   // real tokens
static constexpr int GP   = 320;   // padded tokens (10 x 32)
static constexpr int NTI  = GP / 32;  // 10 token tiles

typedef unsigned short u16;
typedef short bf16x8 __attribute__((ext_vector_type(8)));
typedef float f32x4 __attribute__((ext_vector_type(4)));

#define MFMA(a, b, c) __builtin_amdgcn_mfma_f32_16x16x32_bf16((a), (b), (c), 0, 0, 0)

__device__ __forceinline__ u16 f2bf(float f) {
    union { float f; unsigned u; } v; v.f = f;
    unsigned r = v.u + 0x7FFFu + ((v.u >> 16) & 1u);
    return (u16)(r >> 16);
}

// ---------------- wave/block reduction helpers (wave = 64) ----------------
__device__ __forceinline__ float waveReduceSum(float v) {
    for (int o = 32; o > 0; o >>= 1) v += __shfl_down(v, o, 64);
    return v;
}
__device__ __forceinline__ float waveReduceMax(float v) {
    for (int o = 32; o > 0; o >>= 1) v = fmaxf(v, __shfl_down(v, o, 64));
    return v;
}
__device__ __forceinline__ float blockReduceSum(float v, float* red) {
    int lane = threadIdx.x & 63;
    int w    = threadIdx.x >> 6;
    int nw   = (blockDim.x + 63) >> 6;
    v = waveReduceSum(v);
    if (lane == 0) red[w] = v;
    __syncthreads();
    if (threadIdx.x < 64) {
        float x = (lane < nw) ? red[lane] : 0.0f;
        x = waveReduceSum(x);
        if (lane == 0) red[0] = x;
    }
    __syncthreads();
    float r = red[0];
    __syncthreads();
    return r;
}
__device__ __forceinline__ float blockReduceMax(float v, float* red) {
    int lane = threadIdx.x & 63;
    int w    = threadIdx.x >> 6;
    int nw   = (blockDim.x + 63) >> 6;
    v = waveReduceMax(v);
    if (lane == 0) red[w] = v;
    __syncthreads();
    if (threadIdx.x < 64) {
        float x = (lane < nw) ? red[lane] : -INFINITY;
        x = waveReduceMax(x);
        if (lane == 0) red[0] = x;
    }
    __syncthreads();
    float r = red[0];
    __syncthreads();
    return r;
}

// ------------- prep: transpose encoder weights to bf16 [N][K] -------------
// per-layer layout in wT (shorts): wqT(65536) wkT(65536) wvT(65536) woT(65536)
//                                  w1T[FFH][E](131072) w2T[E][FFH](131072)
__global__ __launch_bounds__(256) void prep_kernel(
    const float* __restrict__ wq, const float* __restrict__ wk,
    const float* __restrict__ wv, const float* __restrict__ wo,
    const float* __restrict__ wf1, const float* __restrict__ wf2,
    u16* __restrict__ wT)
{
    int l = blockIdx.y / 6, m = blockIdx.y % 6;
    int idx = blockIdx.x * 256 + threadIdx.x;
    u16* dst = wT + (size_t)l * 524288;
    if (m < 4) {
        if (idx >= EE * EE) return;
        const float* src = (m == 0 ? wq : m == 1 ? wk : m == 2 ? wv : wo) + (size_t)l * EE * EE;
        int r = idx >> 8, c = idx & 255;           // out[r=eo][c=ei] = in[ei][eo]
        dst[m * 65536 + idx] = f2bf(src[(size_t)c * EE + r]);
    } else if (m == 4) {
        if (idx >= FFH * EE) return;
        const float* src = wf1 + (size_t)l * EE * FFH;
        int r = idx >> 8, c = idx & 255;           // out[f][e] = wf1[e][f]
        dst[262144 + idx] = f2bf(src[(size_t)c * FFH + r]);
    } else {
        if (idx >= EE * FFH) return;
        const float* src = wf2 + (size_t)l * FFH * EE;
        int r = idx >> 9, c = idx & 511;           // out[e][f] = wf2[f][e]
        dst[393216 + idx] = f2bf(src[(size_t)c * EE + r]);
    }
}

// ---------------- embed: 3 small MLPs -> h (fp32) + hb (bf16) ----------------
__global__ __launch_bounds__(256) void embed_kernel(
    const float* __restrict__ obs,
    const float* __restrict__ wi1, const float* __restrict__ bi1,
    const float* __restrict__ wi2, const float* __restrict__ bi2,
    const float* __restrict__ wl1, const float* __restrict__ bl1,
    const float* __restrict__ wl2, const float* __restrict__ bl2,
    const float* __restrict__ wn1, const float* __restrict__ bn1,
    const float* __restrict__ wn2, const float* __restrict__ bn2,
    float* __restrict__ h, u16* __restrict__ hb)
{
    int g = blockIdx.x;             // 0..GP-1
    int b = blockIdx.y;
    int t = threadIdx.x;
    size_t o = ((size_t)b * GP + g) * EE + t;
    if (g >= GG) { h[o] = 0.0f; hb[o] = 0; return; }

    const float* x = obs + ((size_t)b * GG + g) * 9;
    const float *w1, *b1, *w2, *b2;
    int ind;
    if (g < IHN)            { w1 = wi1; b1 = bi1; w2 = wi2; b2 = bi2; ind = ILN; }
    else if (g < IHN + LHN) { w1 = wl1; b1 = bl1; w2 = wl2; b2 = bl2; ind = 8;  }
    else                    { w1 = wn1; b1 = bn1; w2 = wn2; b2 = bn2; ind = 6;  }

    __shared__ float xs[8];
    __shared__ float hid[32];
    if (t < ind) xs[t] = x[t];
    __syncthreads();
    if (t < 32) {
        float a = b1[t];
        for (int i = 0; i < ind; i++) a += xs[i] * w1[i * 32 + t];
        hid[t] = (a > 0.0f) ? a : 0.01f * a;
    }
    __syncthreads();
    float a = b2[t];
    #pragma unroll
    for (int j = 0; j < 32; j++) a += hid[j] * w2[j * EE + t];
    h[o] = a; hb[o] = f2bf(a);
}

// ---------------- K + V(transposed) projection, MFMA ----------------
__global__ __launch_bounds__(256) void kv_kernel(
    const u16* __restrict__ hb, const u16* __restrict__ wkT,
    const u16* __restrict__ wvT, u16* __restrict__ kb, u16* __restrict__ vt)
{
    __shared__ u16 tile[32][264];
    int b = blockIdx.y, t0 = blockIdx.x * 32;
    int tid = threadIdx.x, w = tid >> 6, lane = tid & 63;
    int m = w & 1, nh = w >> 1;
    int lr = lane & 15, lk = (lane >> 4) << 3, lrg = (lane >> 4) << 2;

    const u16* ap = hb + (((size_t)b * GP + t0 + m * 16 + lr) << 8) + lk;
    bf16x8 af[8];
    #pragma unroll
    for (int k = 0; k < 8; k++) af[k] = *(const bf16x8*)(ap + k * 32);

    for (int pass = 0; pass < 2; pass++) {
        const u16* wT = pass ? wvT : wkT;
        f32x4 acc[8];
        #pragma unroll
        for (int n = 0; n < 8; n++) acc[n] = {0.0f, 0.0f, 0.0f, 0.0f};
        for (int k = 0; k < 8; k++) {
            #pragma unroll
            for (int n = 0; n < 8; n++) {
                const u16* bp = wT + (((size_t)(nh * 128 + n * 16 + lr)) << 8) + k * 32 + lk;
                acc[n] = MFMA(af[k], *(const bf16x8*)bp, acc[n]);
            }
        }
        #pragma unroll
        for (int n = 0; n < 8; n++)
            #pragma unroll
            for (int r = 0; r < 4; r++)
                tile[m * 16 + lrg + r][nh * 128 + n * 16 + lr] = f2bf(acc[n][r]);
        __syncthreads();
        if (pass == 0) {
            for (int r = 0; r < 32; r++)
                kb[(((size_t)b * GP + t0 + r) << 8) + tid] = tile[r][tid];
        } else {
            u16 tmp[32];
            #pragma unroll
            for (int r = 0; r < 32; r++) tmp[r] = tile[r][tid];
            u16* dst = vt + ((size_t)b * EE + tid) * GP + t0;
            #pragma unroll
            for (int r = 0; r < 32; r += 4) {
                ushort4 v4 = make_ushort4(tmp[r], tmp[r + 1], tmp[r + 2], tmp[r + 3]);
                *(ushort4*)(dst + r) = v4;
            }
        }
        __syncthreads();
    }
}

// ------- fused attention: Q, S=QK^T, softmax(in-reg), PV, WO, res, LN -------
__global__ __launch_bounds__(256) void attn_kernel(
    float* __restrict__ h, u16* __restrict__ hb,
    const u16* __restrict__ kb, const u16* __restrict__ vt,
    const u16* __restrict__ wqT, const u16* __restrict__ woT,
    const float* __restrict__ obs)
{
    __shared__ __align__(16) char smem[39936];
    u16*  sQ    = (u16*)smem;               // [32][264], later reused as ao
    u16*  sP    = (u16*)(smem + 16896);     // [32][328]
    float* sBias = (float*)(smem + 37888);  // [320]
    float* sPm   = (float*)(smem + 39168);  // [2][32]
    float* sPs   = (float*)(smem + 39424);  // [2][32]
    float* sMean = (float*)(smem + 39680);  // [32]
    float* sRstd = (float*)(smem + 39808);  // [32]
    float* st    = (float*)smem;            // [32][260] overlay (post-WO)

    int b = blockIdx.y, t0 = blockIdx.x * 32;
    int tid = threadIdx.x, w = tid >> 6, lane = tid & 63;
    int m = w & 1, nh = w >> 1;
    int lr = lane & 15, lk = (lane >> 4) << 3, lrg = (lane >> 4) << 2;

    // attention bias for all 320 key slots (pads -> -1e9)
    {
        float msk = (tid < GG) ? obs[((size_t)b * GG + tid) * 9 + 8] : 0.0f;
        sBias[tid] = (1.0f - msk) * -1e9f;
        if (tid < 64) {
            int j2 = 256 + tid;
            float m2 = (j2 < GG) ? obs[((size_t)b * GG + j2) * 9 + 8] : 0.0f;
            sBias[j2] = (1.0f - m2) * -1e9f;
        }
    }

    // ---- Q = hb_tile @ wqT -> sQ (bf16) ----
    {
        const u16* ap = hb + (((size_t)b * GP + t0 + m * 16 + lr) << 8) + lk;
        bf16x8 af[8];
        #pragma unroll
        for (int k = 0; k < 8; k++) af[k] = *(const bf16x8*)(ap + k * 32);
        f32x4 acc[8];
        #pragma unroll
        for (int n = 0; n < 8; n++) acc[n] = {0.0f, 0.0f, 0.0f, 0.0f};
        for (int k = 0; k < 8; k++) {
            #pragma unroll
            for (int n = 0; n < 8; n++) {
                const u16* bp = wqT + (((size_t)(nh * 128 + n * 16 + lr)) << 8) + k * 32 + lk;
                acc[n] = MFMA(af[k], *(const bf16x8*)bp, acc[n]);
            }
        }
        #pragma unroll
        for (int n = 0; n < 8; n++)
            #pragma unroll
            for (int r = 0; r < 4; r++)
                sQ[(m * 16 + lrg + r) * 264 + nh * 128 + n * 16 + lr] = f2bf(acc[n][r]);
    }
    __syncthreads();

    // ---- scores: wave handles rows m*16.., j-tiles nh*10..nh*10+9 ----
    f32x4 sacc[10];
    #pragma unroll
    for (int nn = 0; nn < 10; nn++) sacc[nn] = {0.0f, 0.0f, 0.0f, 0.0f};
    for (int k = 0; k < 8; k++) {
        bf16x8 af = *(const bf16x8*)(sQ + (m * 16 + lr) * 264 + k * 32 + lk);
        #pragma unroll
        for (int nn = 0; nn < 10; nn++) {
            int jt = nh * 10 + nn;
            const u16* bp = kb + (((size_t)b * GP + jt * 16 + lr) << 8) + k * 32 + lk;
            sacc[nn] = MFMA(af, *(const bf16x8*)bp, sacc[nn]);
        }
    }
    #pragma unroll
    for (int nn = 0; nn < 10; nn++) {
        float bia = sBias[(nh * 10 + nn) * 16 + lr];
        #pragma unroll
        for (int r = 0; r < 4; r++) sacc[nn][r] = sacc[nn][r] * 0.0625f + bia;
    }
    // row max (16 lanes of a group share the 4 rows lrg..lrg+3)
    #pragma unroll
    for (int r = 0; r < 4; r++) {
        float mx = -1e30f;
        #pragma unroll
        for (int nn = 0; nn < 10; nn++) mx = fmaxf(mx, sacc[nn][r]);
        mx = fmaxf(mx, __shfl_xor(mx, 1));
        mx = fmaxf(mx, __shfl_xor(mx, 2));
        mx = fmaxf(mx, __shfl_xor(mx, 4));
        mx = fmaxf(mx, __shfl_xor(mx, 8));
        if (lr == 0) sPm[nh * 32 + m * 16 + lrg + r] = mx;
    }
    __syncthreads();
    #pragma unroll
    for (int r = 0; r < 4; r++) {
        int row = m * 16 + lrg + r;
        float rm = fmaxf(sPm[row], sPm[32 + row]);
        float ss = 0.0f;
        #pragma unroll
        for (int nn = 0; nn < 10; nn++) {
            float e = __expf(sacc[nn][r] - rm);
            sacc[nn][r] = e;
            ss += e;
        }
        ss += __shfl_xor(ss, 1);
        ss += __shfl_xor(ss, 2);
        ss += __shfl_xor(ss, 4);
        ss += __shfl_xor(ss, 8);
        if (lr == 0) sPs[nh * 32 + row] = ss;
    }
    __syncthreads();
    #pragma unroll
    for (int r = 0; r < 4; r++) {
        int row = m * 16 + lrg + r;
        float rinv = 1.0f / (sPs[row] + sPs[32 + row]);
        #pragma unroll
        for (int nn = 0; nn < 10; nn++)
            sP[row * 328 + (nh * 10 + nn) * 16 + lr] = f2bf(sacc[nn][r] * rinv);
    }
    __syncthreads();

    // ---- PV: out[32][256] = P[32][320] @ V[320][256] (B-frags from vt) ----
    f32x4 oacc[8];
    #pragma unroll
    for (int n = 0; n < 8; n++) oacc[n] = {0.0f, 0.0f, 0.0f, 0.0f};
    for (int ks = 0; ks < 10; ks++) {
        bf16x8 af = *(const bf16x8*)(sP + (m * 16 + lr) * 328 + ks * 32 + lk);
        #pragma unroll
        for (int n = 0; n < 8; n++) {
            int e = nh * 128 + n * 16 + lr;
            const u16* bp = vt + ((size_t)b * EE + e) * GP + ks * 32 + lk;
            oacc[n] = MFMA(af, *(const bf16x8*)bp, oacc[n]);
        }
    }
    // ao (attention out, bf16) overlays sQ (dead since scores phase)
    #pragma unroll
    for (int n = 0; n < 8; n++)
        #pragma unroll
        for (int r = 0; r < 4; r++)
            sQ[(m * 16 + lrg + r) * 264 + nh * 128 + n * 16 + lr] = f2bf(oacc[n][r]);
    __syncthreads();

    // ---- WO ----
    f32x4 wacc[8];
    #pragma unroll
    for (int n = 0; n < 8; n++) wacc[n] = {0.0f, 0.0f, 0.0f, 0.0f};
    for (int k = 0; k < 8; k++) {
        bf16x8 af = *(const bf16x8*)(sQ + (m * 16 + lr) * 264 + k * 32 + lk);
        #pragma unroll
        for (int n = 0; n < 8; n++) {
            const u16* bp = woT + (((size_t)(nh * 128 + n * 16 + lr)) << 8) + k * 32 + lk;
            wacc[n] = MFMA(af, *(const bf16x8*)bp, wacc[n]);
        }
    }
    __syncthreads();   // everyone done reading ao -> st overlay safe

    #pragma unroll
    for (int n = 0; n < 8; n++)
        #pragma unroll
        for (int r = 0; r < 4; r++) {
            int row = m * 16 + lrg + r, col = nh * 128 + n * 16 + lr;
            st[row * 260 + col] = wacc[n][r] + h[(((size_t)b * GP + t0 + row) << 8) + col];
        }
    __syncthreads();

    // ---- LN ----
    {
        int row = tid >> 3, sl = tid & 7;
        float s1 = 0.0f, s2 = 0.0f;
        #pragma unroll
        for (int i = 0; i < 32; i++) {
            float v = st[row * 260 + sl + i * 8];
            s1 += v; s2 += v * v;
        }
        s1 += __shfl_xor(s1, 1); s2 += __shfl_xor(s2, 1);
        s1 += __shfl_xor(s1, 2); s2 += __shfl_xor(s2, 2);
        s1 += __shfl_xor(s1, 4); s2 += __shfl_xor(s2, 4);
        if (sl == 0) {
            float mean = s1 * (1.0f / 256.0f);
            float var = s2 * (1.0f / 256.0f) - mean * mean;
            sMean[row] = mean;
            sRstd[row] = rsqrtf(var + 1e-5f);
        }
    }
    __syncthreads();
    for (int r = 0; r < 32; r++) {
        float v = (st[r * 260 + tid] - sMean[r]) * sRstd[r];
        size_t o = (((size_t)b * GP + t0 + r) << 8) + tid;
        h[o] = v; hb[o] = f2bf(v);
    }
}

// ------------- fused FF: relu(h@wf1+b1)@wf2+b2 + residual + LN -------------
__global__ __launch_bounds__(256) void ff_kernel(
    float* __restrict__ h, u16* __restrict__ hb,
    const u16* __restrict__ w1T, const float* __restrict__ bf1,
    const u16* __restrict__ w2T, const float* __restrict__ bf2)
{
    __shared__ __align__(16) char smem[33536];
    u16* hid = (u16*)smem;                // [32][520]
    float* st = (float*)smem;             // [32][260] overlay (post-FF2)
    float* sMean = (float*)(smem + 33280);
    float* sRstd = (float*)(smem + 33408);

    int b = blockIdx.y, t0 = blockIdx.x * 32;
    int tid = threadIdx.x, w = tid >> 6, lane = tid & 63;
    int m = w & 1, nh = w >> 1;
    int lr = lane & 15, lk = (lane >> 4) << 3, lrg = (lane >> 4) << 2;

    const u16* ap = hb + (((size_t)b * GP + t0 + m * 16 + lr) << 8) + lk;
    bf16x8 af[8];
    #pragma unroll
    for (int k = 0; k < 8; k++) af[k] = *(const bf16x8*)(ap + k * 32);

    // FF1: wave -> 16 f-tiles (nh half of 512)
    f32x4 acc[16];
    #pragma unroll
    for (int n = 0; n < 16; n++) acc[n] = {0.0f, 0.0f, 0.0f, 0.0f};
    for (int k = 0; k < 8; k++) {
        #pragma unroll
        for (int n = 0; n < 16; n++) {
            const u16* bp = w1T + (((size_t)(nh * 256 + n * 16 + lr)) << 8) + k * 32 + lk;
            acc[n] = MFMA(af[k], *(const bf16x8*)bp, acc[n]);
        }
    }
    #pragma unroll
    for (int n = 0; n < 16; n++) {
        int f = nh * 256 + n * 16 + lr;
        float bias = bf1[f];
        #pragma unroll
        for (int r = 0; r < 4; r++) {
            float v = acc[n][r] + bias;
            hid[(m * 16 + lrg + r) * 520 + f] = f2bf(fmaxf(v, 0.0f));
        }
    }
    __syncthreads();

    // FF2: K=512 (16 ksteps)
    f32x4 acc2[8];
    #pragma unroll
    for (int n = 0; n < 8; n++) acc2[n] = {0.0f, 0.0f, 0.0f, 0.0f};
    for (int ks = 0; ks < 16; ks++) {
        bf16x8 a2 = *(const bf16x8*)(hid + (m * 16 + lr) * 520 + ks * 32 + lk);
        #pragma unroll
        for (int n = 0; n < 8; n++) {
            const u16* bp = w2T + ((size_t)(nh * 128 + n * 16 + lr)) * FFH + ks * 32 + lk;
            acc2[n] = MFMA(a2, *(const bf16x8*)bp, acc2[n]);
        }
    }
    __syncthreads();   // hid reads done -> st overlay safe

    #pragma unroll
    for (int n = 0; n < 8; n++)
        #pragma unroll
        for (int r = 0; r < 4; r++) {
            int row = m * 16 + lrg + r, col = nh * 128 + n * 16 + lr;
            st[row * 260 + col] = acc2[n][r] + bf2[col] + h[(((size_t)b * GP + t0 + row) << 8) + col];
        }
    __syncthreads();

    {
        int row = tid >> 3, sl = tid & 7;
        float s1 = 0.0f, s2 = 0.0f;
        #pragma unroll
        for (int i = 0; i < 32; i++) {
            float v = st[row * 260 + sl + i * 8];
            s1 += v; s2 += v * v;
        }
        s1 += __shfl_xor(s1, 1); s2 += __shfl_xor(s2, 1);
        s1 += __shfl_xor(s1, 2); s2 += __shfl_xor(s2, 2);
        s1 += __shfl_xor(s1, 4); s2 += __shfl_xor(s2, 4);
        if (sl == 0) {
            float mean = s1 * (1.0f / 256.0f);
            float var = s2 * (1.0f / 256.0f) - mean * mean;
            sMean[row] = mean;
            sRstd[row] = rsqrtf(var + 1e-5f);
        }
    }
    __syncthreads();
    for (int r = 0; r < 32; r++) {
        float v = (st[r * 260 + tid] - sMean[r]) * sRstd[r];
        size_t o = (((size_t)b * GP + t0 + r) << 8) + tid;
        h[o] = v; hb[o] = f2bf(v);
    }
}

// ------------- head part 1: graph embed -> fixed context -> u[b] -------------
__global__ __launch_bounds__(256) void final1_kernel(
    const float* __restrict__ h, const float* __restrict__ obs,
    const float* __restrict__ w_fc, const float* __restrict__ w_pn,
    float* __restrict__ u)
{
    int b = blockIdx.x;
    int t = threadIdx.x;
    __shared__ float ges[EE];
    __shared__ float fcs[EE];

    float acc = 0.0f, vlen = 0.0f;
    for (int g = 0; g < GG; g++) {
        float m = obs[((size_t)b * GG + g) * 9 + 8];
        vlen += m;
        acc += h[((size_t)b * GP + g) * EE + t] * m;
    }
    ges[t] = acc / vlen;
    __syncthreads();

    float fc = 0.0f;
    for (int kk = 0; kk < EE; kk++) fc += ges[kk] * w_fc[kk * EE + t];
    fcs[t] = fc;
    __syncthreads();

    const float4* wp = reinterpret_cast<const float4*>(w_pn + (size_t)t * 3 * EE);
    float ua = 0.0f;
    for (int kk = 0; kk < EE / 4; kk++) {
        float4 w = wp[kk];
        ua += w.x * fcs[kk * 4] + w.y * fcs[kk * 4 + 1] +
              w.z * fcs[kk * 4 + 2] + w.w * fcs[kk * 4 + 3];
    }
    u[(size_t)b * EE + t] = ua;
}

// ------------- head part 2: compat -> tanh clip -> masked softmax -------------
__global__ __launch_bounds__(128) void final2_kernel(
    const float* __restrict__ h, const float* __restrict__ obs,
    const float* __restrict__ u, float* __restrict__ out)
{
    int b = blockIdx.x;
    int t = threadIdx.x;  // 128 threads
    __shared__ float us[EE];
    __shared__ float red[8];
    us[t]       = u[(size_t)b * EE + t];
    us[t + 128] = u[(size_t)b * EE + t + 128];
    __syncthreads();

    float logit = -INFINITY;
    float m = 0.0f;
    if (t < LHN) {
        int g = IHN + t;
        m = obs[((size_t)b * GG + g) * 9 + 8];
        const float4* hr = reinterpret_cast<const float4*>(h + ((size_t)b * GP + g) * EE);
        float c = 0.0f;
        for (int kk = 0; kk < EE / 4; kk++) {
            float4 hv = hr[kk];
            c += hv.x * us[kk * 4] + hv.y * us[kk * 4 + 1] +
                 hv.z * us[kk * 4 + 2] + hv.w * us[kk * 4 + 3];
        }
        c *= m;
        c *= 0.0625f;
        logit = tanhf(c) * 10.0f;
    }
    float bm = blockReduceMax(logit, red);
    float e  = (t < LHN) ? __expf(logit - bm) : 0.0f;
    float bs = blockReduceSum(e, red);
    float p  = e / bs;
    float masked = (t < LHN) ? (p * m + 1e-20f) : 0.0f;
    float bs2 = blockReduceSum(masked, red);
    if (t < LHN) out[(size_t)b * LHN + t] = masked / bs2;
}

extern "C" void kernel_launch(void* const* d_in, const int* in_sizes, int n_in,
                              void* d_out, int out_size, void* d_ws, size_t ws_size,
                              hipStream_t stream) {
    const float* obs   = (const float*)d_in[0];
    const float* wi1   = (const float*)d_in[1];
    const float* bi1   = (const float*)d_in[2];
    const float* wi2   = (const float*)d_in[3];
    const float* bi2   = (const float*)d_in[4];
    const float* wl1   = (const float*)d_in[5];
    const float* bl1   = (const float*)d_in[6];
    const float* wl2   = (const float*)d_in[7];
    const float* bl2   = (const float*)d_in[8];
    const float* wn1   = (const float*)d_in[9];
    const float* bn1   = (const float*)d_in[10];
    const float* wn2   = (const float*)d_in[11];
    const float* bn2   = (const float*)d_in[12];
    const float* e_wq  = (const float*)d_in[13];
    const float* e_wk  = (const float*)d_in[14];
    const float* e_wv  = (const float*)d_in[15];
    const float* e_wo  = (const float*)d_in[16];
    const float* e_wf1 = (const float*)d_in[17];
    const float* e_bf1 = (const float*)d_in[18];
    const float* e_wf2 = (const float*)d_in[19];
    const float* e_bf2 = (const float*)d_in[20];
    const float* w_pn  = (const float*)d_in[21];
    const float* w_fc  = (const float*)d_in[22];
    float* outp = (float*)d_out;

    char* wsc = (char*)d_ws;
    float* h   = (float*)wsc;                       //  83,886,080 B
    u16*   hb  = (u16*)(wsc + 83886080);            //  41,943,040 B
    u16*   kb  = (u16*)(wsc + 125829120);           //  41,943,040 B
    u16*   vt  = (u16*)(wsc + 167772160);           //  41,943,040 B
    u16*   wT  = (u16*)(wsc + 209715200);           //   2,097,152 B
    float* ubuf= (float*)(wsc + 211812352);         //     262,144 B

    prep_kernel<<<dim3(512, 12), 256, 0, stream>>>(e_wq, e_wk, e_wv, e_wo, e_wf1, e_wf2, wT);
    embed_kernel<<<dim3(GP, BB), 256, 0, stream>>>(obs, wi1, bi1, wi2, bi2,
                                                   wl1, bl1, wl2, bl2,
                                                   wn1, bn1, wn2, bn2, h, hb);
    const size_t WL = 524288;
    for (int l = 0; l < NL; l++) {
        u16* wqT = wT + l * WL;
        u16* wkT = wqT + 65536;
        u16* wvT = wqT + 131072;
        u16* woT = wqT + 196608;
        u16* w1T = wqT + 262144;
        u16* w2T = wqT + 393216;
        const float* bf1 = e_bf1 + (size_t)l * FFH;
        const float* bf2 = e_bf2 + (size_t)l * EE;
        kv_kernel<<<dim3(NTI, BB), 256, 0, stream>>>(hb, wkT, wvT, kb, vt);
        attn_kernel<<<dim3(NTI, BB), 256, 0, stream>>>(h, hb, kb, vt, wqT, woT, obs);
        ff_kernel<<<dim3(NTI, BB), 256, 0, stream>>>(h, hb, w1T, bf1, w2T, bf2);
    }
    final1_kernel<<<BB, 256, 0, stream>>>(h, obs, w_fc, w_pn, ubuf);
    final2_kernel<<<BB, 128, 0, stream>>>(h, obs, ubuf, outp);
}

// Round 4
// 965.138 us; speedup vs baseline: 5.9009x; 2.1167x over previous
//
#include <hip/hip_runtime.h>
#include <math.h>

static constexpr int BB   = 256;   // batch
static constexpr int IHN  = 200;   // internal tokens
static constexpr int ILN  = 6;     // internal feature dim
static constexpr int LHN  = 100;   // leaf tokens
static constexpr int EE   = 256;   // embed dim
static constexpr int FFH  = 512;   // ff hidden
static constexpr int NL   = 2;     // layers
static constexpr int GG   = 301;   // real tokens
static constexpr int GP   = 320;   // padded tokens (10 x 32)
static constexpr int MT   = BB * GP;  // 81920 total token rows (640 x 128)

typedef unsigned short u16;
typedef short bf16x8 __attribute__((ext_vector_type(8)));
typedef float f32x4 __attribute__((ext_vector_type(4)));

#define MFMA(a, b, c) __builtin_amdgcn_mfma_f32_16x16x32_bf16((a), (b), (c), 0, 0, 0)

__device__ __forceinline__ u16 f2bf(float f) {
    union { float f; unsigned u; } v; v.f = f;
    unsigned r = v.u + 0x7FFFu + ((v.u >> 16) & 1u);
    return (u16)(r >> 16);
}

// ---------------- wave/block reduction helpers (wave = 64) ----------------
__device__ __forceinline__ float waveReduceSum(float v) {
    for (int o = 32; o > 0; o >>= 1) v += __shfl_down(v, o, 64);
    return v;
}
__device__ __forceinline__ float waveReduceMax(float v) {
    for (int o = 32; o > 0; o >>= 1) v = fmaxf(v, __shfl_down(v, o, 64));
    return v;
}
__device__ __forceinline__ float blockReduceSum(float v, float* red) {
    int lane = threadIdx.x & 63;
    int w    = threadIdx.x >> 6;
    int nw   = (blockDim.x + 63) >> 6;
    v = waveReduceSum(v);
    if (lane == 0) red[w] = v;
    __syncthreads();
    if (threadIdx.x < 64) {
        float x = (lane < nw) ? red[lane] : 0.0f;
        x = waveReduceSum(x);
        if (lane == 0) red[0] = x;
    }
    __syncthreads();
    float r = red[0];
    __syncthreads();
    return r;
}
__device__ __forceinline__ float blockReduceMax(float v, float* red) {
    int lane = threadIdx.x & 63;
    int w    = threadIdx.x >> 6;
    int nw   = (blockDim.x + 63) >> 6;
    v = waveReduceMax(v);
    if (lane == 0) red[w] = v;
    __syncthreads();
    if (threadIdx.x < 64) {
        float x = (lane < nw) ? red[lane] : -INFINITY;
        x = waveReduceMax(x);
        if (lane == 0) red[0] = x;
    }
    __syncthreads();
    float r = red[0];
    __syncthreads();
    return r;
}

// --------- staging: global -> LDS tile [rows][64] bf16, XOR-swizzled ---------
// LDS linear byte o: row = o>>7, colbyte = (o&127) ^ ((row&7)<<4).
// Pre-swizzle the global SOURCE so LDS dest stays linear (global_load_lds rule).
__device__ __forceinline__ void stage_swz(const u16* src, int strideShorts, int k0,
                                          u16* ldsTile, int nChunks, int wave,
                                          int nWaves, int lane)
{
    for (int c = wave; c < nChunks; c += nWaves) {
        int o = c * 1024 + lane * 16;
        int row = o >> 7;
        int cb = (o & 127) ^ ((row & 7) << 4);
        const u16* g = src + (size_t)row * strideShorts + k0 + (cb >> 1);
        __builtin_amdgcn_global_load_lds(
            (const __attribute__((address_space(1))) unsigned int*)g,
            (__attribute__((address_space(3))) unsigned int*)((char*)ldsTile + c * 1024),
            16, 0, 0);
    }
}

// swizzled LDS read of one bf16x8 fragment: logical (row, k-chunk kk, quarter q)
__device__ __forceinline__ bf16x8 lds_frag(const u16* tile, int row, int kk, int q)
{
    int cb = (kk * 64 + q * 16) ^ ((row & 7) << 4);
    return *(const bf16x8*)((const char*)tile + row * 128 + cb);
}

// ------------- prep: transpose encoder weights to bf16 [N][K] -------------
// per-layer (shorts): wqT(65536) wkT wvT woT  w1T[512][256]  w2T[256][512]
__global__ __launch_bounds__(256) void prep_kernel(
    const float* __restrict__ wq, const float* __restrict__ wk,
    const float* __restrict__ wv, const float* __restrict__ wo,
    const float* __restrict__ wf1, const float* __restrict__ wf2,
    u16* __restrict__ wT)
{
    int l = blockIdx.y / 6, m = blockIdx.y % 6;
    int idx = blockIdx.x * 256 + threadIdx.x;
    u16* dst = wT + (size_t)l * 524288;
    if (m < 4) {
        if (idx >= EE * EE) return;
        const float* src = (m == 0 ? wq : m == 1 ? wk : m == 2 ? wv : wo) + (size_t)l * EE * EE;
        int r = idx >> 8, c = idx & 255;
        dst[m * 65536 + idx] = f2bf(src[(size_t)c * EE + r]);
    } else if (m == 4) {
        if (idx >= FFH * EE) return;
        const float* src = wf1 + (size_t)l * EE * FFH;
        int r = idx >> 8, c = idx & 255;
        dst[262144 + idx] = f2bf(src[(size_t)c * FFH + r]);
    } else {
        if (idx >= EE * FFH) return;
        const float* src = wf2 + (size_t)l * FFH * EE;
        int r = idx >> 9, c = idx & 511;
        dst[393216 + idx] = f2bf(src[(size_t)c * EE + r]);
    }
}

// ---------------- embed: 3 small MLPs -> h (fp32) + hb (bf16) ----------------
__global__ __launch_bounds__(256) void embed_kernel(
    const float* __restrict__ obs,
    const float* __restrict__ wi1, const float* __restrict__ bi1,
    const float* __restrict__ wi2, const float* __restrict__ bi2,
    const float* __restrict__ wl1, const float* __restrict__ bl1,
    const float* __restrict__ wl2, const float* __restrict__ bl2,
    const float* __restrict__ wn1, const float* __restrict__ bn1,
    const float* __restrict__ wn2, const float* __restrict__ bn2,
    float* __restrict__ h, u16* __restrict__ hb)
{
    int g = blockIdx.x;
    int b = blockIdx.y;
    int t = threadIdx.x;
    size_t o = ((size_t)b * GP + g) * EE + t;
    if (g >= GG) { h[o] = 0.0f; hb[o] = 0; return; }

    const float* x = obs + ((size_t)b * GG + g) * 9;
    const float *w1, *b1, *w2, *b2;
    int ind;
    if (g < IHN)            { w1 = wi1; b1 = bi1; w2 = wi2; b2 = bi2; ind = ILN; }
    else if (g < IHN + LHN) { w1 = wl1; b1 = bl1; w2 = wl2; b2 = bl2; ind = 8;  }
    else                    { w1 = wn1; b1 = bn1; w2 = wn2; b2 = bn2; ind = 6;  }

    __shared__ float xs[8];
    __shared__ float hid[32];
    if (t < ind) xs[t] = x[t];
    __syncthreads();
    if (t < 32) {
        float a = b1[t];
        for (int i = 0; i < ind; i++) a += xs[i] * w1[i * 32 + t];
        hid[t] = (a > 0.0f) ? a : 0.01f * a;
    }
    __syncthreads();
    float a = b2[t];
    #pragma unroll
    for (int j = 0; j < 32; j++) a += hid[j] * w2[j * EE + t];
    h[o] = a; hb[o] = f2bf(a);
}

// --------- QKV GEMM: 128x128 tile, epilogue scatters Q/K rows + V^T ---------
__global__ __launch_bounds__(256) void qkv_gemm(
    const u16* __restrict__ hb, const u16* __restrict__ wqkvT,
    u16* __restrict__ qb, u16* __restrict__ kb, u16* __restrict__ vt)
{
    __shared__ __align__(16) u16 sA[128 * 64];
    __shared__ __align__(16) u16 sB[128 * 64];
    int tid = threadIdx.x, lane = tid & 63, w = tid >> 6;
    int wm = w >> 1, wn = w & 1;
    int lr = lane & 15, q = lane >> 4;
    int brow = blockIdx.x * 128;
    int bcol = blockIdx.y * 128;

    f32x4 acc[4][4];
    #pragma unroll
    for (int i = 0; i < 4; i++)
        #pragma unroll
        for (int j = 0; j < 4; j++) acc[i][j] = {0.0f, 0.0f, 0.0f, 0.0f};

    for (int ks = 0; ks < 4; ks++) {
        __syncthreads();
        stage_swz(hb + (size_t)brow * 256, 256, ks * 64, sA, 16, w, 4, lane);
        stage_swz(wqkvT + (size_t)bcol * 256, 256, ks * 64, sB, 16, w, 4, lane);
        __syncthreads();
        #pragma unroll
        for (int kk = 0; kk < 2; kk++) {
            bf16x8 a[4], b[4];
            #pragma unroll
            for (int i = 0; i < 4; i++) {
                a[i] = lds_frag(sA, wm * 64 + i * 16 + lr, kk, q);
                b[i] = lds_frag(sB, wn * 64 + i * 16 + lr, kk, q);
            }
            #pragma unroll
            for (int mi = 0; mi < 4; mi++)
                #pragma unroll
                for (int ni = 0; ni < 4; ni++)
                    acc[mi][ni] = MFMA(a[mi], b[ni], acc[mi][ni]);
        }
    }

    if (bcol < 512) {
        u16* dst = (bcol < 256) ? qb : kb;
        int cOff = bcol & 255;
        #pragma unroll
        for (int mi = 0; mi < 4; mi++)
            #pragma unroll
            for (int ni = 0; ni < 4; ni++) {
                int col = cOff + wn * 64 + ni * 16 + lr;
                #pragma unroll
                for (int j = 0; j < 4; j++) {
                    int rowG = brow + wm * 64 + mi * 16 + q * 4 + j;
                    dst[(size_t)rowG * 256 + col] = f2bf(acc[mi][ni][j]);
                }
            }
    } else {
        #pragma unroll
        for (int mi = 0; mi < 4; mi++) {
            int rowG0 = brow + wm * 64 + mi * 16 + q * 4;
            int b0 = rowG0 / GP;
            int g0 = rowG0 - b0 * GP;
            #pragma unroll
            for (int ni = 0; ni < 4; ni++) {
                int e = (bcol - 512) + wn * 64 + ni * 16 + lr;
                ushort4 u4;
                u4.x = f2bf(acc[mi][ni][0]);
                u4.y = f2bf(acc[mi][ni][1]);
                u4.z = f2bf(acc[mi][ni][2]);
                u4.w = f2bf(acc[mi][ni][3]);
                *(ushort4*)(vt + ((size_t)(b0 * EE + e)) * GP + g0) = u4;
            }
        }
    }
}

// --------- FF1 GEMM: 128x128 tile, epilogue bias+relu -> hidb bf16 ---------
__global__ __launch_bounds__(256) void ff1_gemm(
    const u16* __restrict__ hb, const u16* __restrict__ w1T,
    const float* __restrict__ bf1, u16* __restrict__ hidb)
{
    __shared__ __align__(16) u16 sA[128 * 64];
    __shared__ __align__(16) u16 sB[128 * 64];
    int tid = threadIdx.x, lane = tid & 63, w = tid >> 6;
    int wm = w >> 1, wn = w & 1;
    int lr = lane & 15, q = lane >> 4;
    int brow = blockIdx.x * 128;
    int bcol = blockIdx.y * 128;

    f32x4 acc[4][4];
    #pragma unroll
    for (int i = 0; i < 4; i++)
        #pragma unroll
        for (int j = 0; j < 4; j++) acc[i][j] = {0.0f, 0.0f, 0.0f, 0.0f};

    for (int ks = 0; ks < 4; ks++) {
        __syncthreads();
        stage_swz(hb + (size_t)brow * 256, 256, ks * 64, sA, 16, w, 4, lane);
        stage_swz(w1T + (size_t)bcol * 256, 256, ks * 64, sB, 16, w, 4, lane);
        __syncthreads();
        #pragma unroll
        for (int kk = 0; kk < 2; kk++) {
            bf16x8 a[4], b[4];
            #pragma unroll
            for (int i = 0; i < 4; i++) {
                a[i] = lds_frag(sA, wm * 64 + i * 16 + lr, kk, q);
                b[i] = lds_frag(sB, wn * 64 + i * 16 + lr, kk, q);
            }
            #pragma unroll
            for (int mi = 0; mi < 4; mi++)
                #pragma unroll
                for (int ni = 0; ni < 4; ni++)
                    acc[mi][ni] = MFMA(a[mi], b[ni], acc[mi][ni]);
        }
    }

    #pragma unroll
    for (int ni = 0; ni < 4; ni++) {
        int col = bcol + wn * 64 + ni * 16 + lr;
        float bias = bf1[col];
        #pragma unroll
        for (int mi = 0; mi < 4; mi++)
            #pragma unroll
            for (int j = 0; j < 4; j++) {
                int rowG = brow + wm * 64 + mi * 16 + q * 4 + j;
                float v = acc[mi][ni][j] + bias;
                hidb[(size_t)rowG * 512 + col] = f2bf(fmaxf(v, 0.0f));
            }
    }
}

// ---- GEMM + residual + LayerNorm: BM=128, BN=256(full row), 8 waves ----
template<int KSTEPS, int ASTR, int BSTR, bool HASB>
__global__ __launch_bounds__(512) void gemmln_kernel(
    const u16* __restrict__ A, const u16* __restrict__ Bw,
    const float* __restrict__ bias, float* __restrict__ h, u16* __restrict__ hb)
{
    __shared__ __align__(16) u16 sA[128 * 64];   // 16 KB
    __shared__ __align__(16) u16 sB[256 * 64];   // 32 KB
    int tid = threadIdx.x, lane = tid & 63, w = tid >> 6;
    int wm = w >> 2, wn = w & 3;
    int lr = lane & 15, q = lane >> 4;
    int brow = blockIdx.x * 128;

    f32x4 acc[4][4];
    #pragma unroll
    for (int i = 0; i < 4; i++)
        #pragma unroll
        for (int j = 0; j < 4; j++) acc[i][j] = {0.0f, 0.0f, 0.0f, 0.0f};

    for (int ks = 0; ks < KSTEPS; ks++) {
        __syncthreads();
        stage_swz(A + (size_t)brow * ASTR, ASTR, ks * 64, sA, 16, w, 8, lane);
        stage_swz(Bw, BSTR, ks * 64, sB, 32, w, 8, lane);
        __syncthreads();
        #pragma unroll
        for (int kk = 0; kk < 2; kk++) {
            bf16x8 a[4], b[4];
            #pragma unroll
            for (int i = 0; i < 4; i++) {
                a[i] = lds_frag(sA, wm * 64 + i * 16 + lr, kk, q);
                b[i] = lds_frag(sB, wn * 64 + i * 16 + lr, kk, q);
            }
            #pragma unroll
            for (int mi = 0; mi < 4; mi++)
                #pragma unroll
                for (int ni = 0; ni < 4; ni++)
                    acc[mi][ni] = MFMA(a[mi], b[ni], acc[mi][ni]);
        }
    }

    __syncthreads();                     // LDS reads done -> overlay sPart
    float* sPart = (float*)sA;           // [4 wn][128 row][2]

    // vals = acc + bias + residual (in place)
    #pragma unroll
    for (int ni = 0; ni < 4; ni++) {
        int col = wn * 64 + ni * 16 + lr;
        float bv = HASB ? bias[col] : 0.0f;
        #pragma unroll
        for (int mi = 0; mi < 4; mi++)
            #pragma unroll
            for (int j = 0; j < 4; j++) {
                int rowG = brow + wm * 64 + mi * 16 + q * 4 + j;
                acc[mi][ni][j] += bv + h[(size_t)rowG * 256 + col];
            }
    }
    // per-row partial sums (this wave's 64-col stripe)
    #pragma unroll
    for (int mi = 0; mi < 4; mi++)
        #pragma unroll
        for (int j = 0; j < 4; j++) {
            float s1 = 0.0f, s2 = 0.0f;
            #pragma unroll
            for (int ni = 0; ni < 4; ni++) {
                float v = acc[mi][ni][j];
                s1 += v; s2 += v * v;
            }
            s1 += __shfl_xor(s1, 1); s2 += __shfl_xor(s2, 1);
            s1 += __shfl_xor(s1, 2); s2 += __shfl_xor(s2, 2);
            s1 += __shfl_xor(s1, 4); s2 += __shfl_xor(s2, 4);
            s1 += __shfl_xor(s1, 8); s2 += __shfl_xor(s2, 8);
            if (lr == 0) {
                int lrow = wm * 64 + mi * 16 + q * 4 + j;
                sPart[(wn * 128 + lrow) * 2 + 0] = s1;
                sPart[(wn * 128 + lrow) * 2 + 1] = s2;
            }
        }
    __syncthreads();

    #pragma unroll
    for (int mi = 0; mi < 4; mi++)
        #pragma unroll
        for (int j = 0; j < 4; j++) {
            int lrow = wm * 64 + mi * 16 + q * 4 + j;
            float s1 = sPart[lrow * 2] + sPart[(128 + lrow) * 2] +
                       sPart[(256 + lrow) * 2] + sPart[(384 + lrow) * 2];
            float s2 = sPart[lrow * 2 + 1] + sPart[(128 + lrow) * 2 + 1] +
                       sPart[(256 + lrow) * 2 + 1] + sPart[(384 + lrow) * 2 + 1];
            float mean = s1 * (1.0f / 256.0f);
            float var  = s2 * (1.0f / 256.0f) - mean * mean;
            float rstd = rsqrtf(var + 1e-5f);
            int rowG = brow + lrow;
            #pragma unroll
            for (int ni = 0; ni < 4; ni++) {
                int col = wn * 64 + ni * 16 + lr;
                float v = (acc[mi][ni][j] - mean) * rstd;
                size_t o = (size_t)rowG * 256 + col;
                h[o] = v; hb[o] = f2bf(v);
            }
        }
}

// ------- attention core: S=QK^T, softmax(in-reg), PV -> aob -------
// NOTE: aob may alias qb (qb reads happen before barriers; aob writes after;
// each block only touches its own 32 rows of both).
__global__ __launch_bounds__(256) void attn_core(
    const u16* __restrict__ qb, const u16* __restrict__ kb,
    const u16* __restrict__ vt, const float* __restrict__ obs,
    u16* __restrict__ aob)
{
    __shared__ __align__(16) u16 sP[32][328];
    __shared__ float sBias[320];
    __shared__ float sPm[4][32], sPs[4][32];

    int b = blockIdx.y, t0 = blockIdx.x * 32;
    int tid = threadIdx.x, w = tid >> 6, lane = tid & 63;
    int lr = lane & 15, q = lane >> 4, lk = q * 8;

    {
        float msk = obs[((size_t)b * GG + tid) * 9 + 8];   // tid<256<GG
        sBias[tid] = (1.0f - msk) * -1e9f;
        if (tid < 64) {
            int j2 = 256 + tid;
            float m2 = (j2 < GG) ? obs[((size_t)b * GG + j2) * 9 + 8] : 0.0f;
            sBias[j2] = (1.0f - m2) * -1e9f;
        }
    }
    __syncthreads();

    // scores: wave w -> j range [w*80, w*80+80), all 32 q-rows
    f32x4 sacc[2][5];
    #pragma unroll
    for (int mi = 0; mi < 2; mi++)
        #pragma unroll
        for (int jt = 0; jt < 5; jt++) sacc[mi][jt] = {0.0f, 0.0f, 0.0f, 0.0f};

    for (int k = 0; k < 8; k++) {
        bf16x8 a0 = *(const bf16x8*)(qb + ((size_t)(b * GP + t0 + lr)) * 256 + k * 32 + lk);
        bf16x8 a1 = *(const bf16x8*)(qb + ((size_t)(b * GP + t0 + 16 + lr)) * 256 + k * 32 + lk);
        #pragma unroll
        for (int jt = 0; jt < 5; jt++) {
            int j = w * 80 + jt * 16 + lr;
            bf16x8 bb = *(const bf16x8*)(kb + ((size_t)(b * GP + j)) * 256 + k * 32 + lk);
            sacc[0][jt] = MFMA(a0, bb, sacc[0][jt]);
            sacc[1][jt] = MFMA(a1, bb, sacc[1][jt]);
        }
    }
    #pragma unroll
    for (int jt = 0; jt < 5; jt++) {
        float bia = sBias[w * 80 + jt * 16 + lr];
        #pragma unroll
        for (int mi = 0; mi < 2; mi++)
            #pragma unroll
            for (int r = 0; r < 4; r++)
                sacc[mi][jt][r] = sacc[mi][jt][r] * 0.0625f + bia;
    }
    // partial row max over this wave's j range
    #pragma unroll
    for (int mi = 0; mi < 2; mi++)
        #pragma unroll
        for (int r = 0; r < 4; r++) {
            float mx = -1e30f;
            #pragma unroll
            for (int jt = 0; jt < 5; jt++) mx = fmaxf(mx, sacc[mi][jt][r]);
            mx = fmaxf(mx, __shfl_xor(mx, 1));
            mx = fmaxf(mx, __shfl_xor(mx, 2));
            mx = fmaxf(mx, __shfl_xor(mx, 4));
            mx = fmaxf(mx, __shfl_xor(mx, 8));
            if (lr == 0) sPm[w][mi * 16 + q * 4 + r] = mx;
        }
    __syncthreads();
    #pragma unroll
    for (int mi = 0; mi < 2; mi++)
        #pragma unroll
        for (int r = 0; r < 4; r++) {
            int row = mi * 16 + q * 4 + r;
            float rm = fmaxf(fmaxf(sPm[0][row], sPm[1][row]), fmaxf(sPm[2][row], sPm[3][row]));
            float ss = 0.0f;
            #pragma unroll
            for (int jt = 0; jt < 5; jt++) {
                float e = __expf(sacc[mi][jt][r] - rm);
                sacc[mi][jt][r] = e;
                ss += e;
            }
            ss += __shfl_xor(ss, 1);
            ss += __shfl_xor(ss, 2);
            ss += __shfl_xor(ss, 4);
            ss += __shfl_xor(ss, 8);
            if (lr == 0) sPs[w][row] = ss;
        }
    __syncthreads();
    #pragma unroll
    for (int mi = 0; mi < 2; mi++)
        #pragma unroll
        for (int r = 0; r < 4; r++) {
            int row = mi * 16 + q * 4 + r;
            float inv = 1.0f / (sPs[0][row] + sPs[1][row] + sPs[2][row] + sPs[3][row]);
            #pragma unroll
            for (int jt = 0; jt < 5; jt++)
                sP[row][w * 80 + jt * 16 + lr] = f2bf(sacc[mi][jt][r] * inv);
        }
    __syncthreads();

    // PV: wave w -> e range [w*64, w*64+64), all 32 rows
    f32x4 oacc[2][4];
    #pragma unroll
    for (int mi = 0; mi < 2; mi++)
        #pragma unroll
        for (int ni = 0; ni < 4; ni++) oacc[mi][ni] = {0.0f, 0.0f, 0.0f, 0.0f};

    for (int ks = 0; ks < 10; ks++) {
        bf16x8 a0 = *(const bf16x8*)(&sP[lr][ks * 32 + lk]);
        bf16x8 a1 = *(const bf16x8*)(&sP[16 + lr][ks * 32 + lk]);
        #pragma unroll
        for (int ni = 0; ni < 4; ni++) {
            int e = w * 64 + ni * 16 + lr;
            bf16x8 bb = *(const bf16x8*)(vt + ((size_t)(b * EE + e)) * GP + ks * 32 + lk);
            oacc[0][ni] = MFMA(a0, bb, oacc[0][ni]);
            oacc[1][ni] = MFMA(a1, bb, oacc[1][ni]);
        }
    }
    #pragma unroll
    for (int mi = 0; mi < 2; mi++)
        #pragma unroll
        for (int ni = 0; ni < 4; ni++) {
            int col = w * 64 + ni * 16 + lr;
            #pragma unroll
            for (int r = 0; r < 4; r++) {
                int row = mi * 16 + q * 4 + r;
                aob[((size_t)(b * GP + t0 + row)) * 256 + col] = f2bf(oacc[mi][ni][r]);
            }
        }
}

// ------------- head part 1: graph embed -> fixed context -> u[b] -------------
__global__ __launch_bounds__(256) void final1_kernel(
    const float* __restrict__ h, const float* __restrict__ obs,
    const float* __restrict__ w_fc, const float* __restrict__ w_pn,
    float* __restrict__ u)
{
    int b = blockIdx.x;
    int t = threadIdx.x;
    __shared__ float ges[EE];
    __shared__ float fcs[EE];

    float acc = 0.0f, vlen = 0.0f;
    for (int g = 0; g < GG; g++) {
        float m = obs[((size_t)b * GG + g) * 9 + 8];
        vlen += m;
        acc += h[((size_t)b * GP + g) * EE + t] * m;
    }
    ges[t] = acc / vlen;
    __syncthreads();

    float fc = 0.0f;
    for (int kk = 0; kk < EE; kk++) fc += ges[kk] * w_fc[kk * EE + t];
    fcs[t] = fc;
    __syncthreads();

    const float4* wp = reinterpret_cast<const float4*>(w_pn + (size_t)t * 3 * EE);
    float ua = 0.0f;
    for (int kk = 0; kk < EE / 4; kk++) {
        float4 w = wp[kk];
        ua += w.x * fcs[kk * 4] + w.y * fcs[kk * 4 + 1] +
              w.z * fcs[kk * 4 + 2] + w.w * fcs[kk * 4 + 3];
    }
    u[(size_t)b * EE + t] = ua;
}

// ------------- head part 2: compat -> tanh clip -> masked softmax -------------
__global__ __launch_bounds__(128) void final2_kernel(
    const float* __restrict__ h, const float* __restrict__ obs,
    const float* __restrict__ u, float* __restrict__ out)
{
    int b = blockIdx.x;
    int t = threadIdx.x;
    __shared__ float us[EE];
    __shared__ float red[8];
    us[t]       = u[(size_t)b * EE + t];
    us[t + 128] = u[(size_t)b * EE + t + 128];
    __syncthreads();

    float logit = -INFINITY;
    float m = 0.0f;
    if (t < LHN) {
        int g = IHN + t;
        m = obs[((size_t)b * GG + g) * 9 + 8];
        const float4* hr = reinterpret_cast<const float4*>(h + ((size_t)b * GP + g) * EE);
        float c = 0.0f;
        for (int kk = 0; kk < EE / 4; kk++) {
            float4 hv = hr[kk];
            c += hv.x * us[kk * 4] + hv.y * us[kk * 4 + 1] +
                 hv.z * us[kk * 4 + 2] + hv.w * us[kk * 4 + 3];
        }
        c *= m;
        c *= 0.0625f;
        logit = tanhf(c) * 10.0f;
    }
    float bm = blockReduceMax(logit, red);
    float e  = (t < LHN) ? __expf(logit - bm) : 0.0f;
    float bs = blockReduceSum(e, red);
    float p  = e / bs;
    float masked = (t < LHN) ? (p * m + 1e-20f) : 0.0f;
    float bs2 = blockReduceSum(masked, red);
    if (t < LHN) out[(size_t)b * LHN + t] = masked / bs2;
}

extern "C" void kernel_launch(void* const* d_in, const int* in_sizes, int n_in,
                              void* d_out, int out_size, void* d_ws, size_t ws_size,
                              hipStream_t stream) {
    const float* obs   = (const float*)d_in[0];
    const float* wi1   = (const float*)d_in[1];
    const float* bi1   = (const float*)d_in[2];
    const float* wi2   = (const float*)d_in[3];
    const float* bi2   = (const float*)d_in[4];
    const float* wl1   = (const float*)d_in[5];
    const float* bl1   = (const float*)d_in[6];
    const float* wl2   = (const float*)d_in[7];
    const float* bl2   = (const float*)d_in[8];
    const float* wn1   = (const float*)d_in[9];
    const float* bn1   = (const float*)d_in[10];
    const float* wn2   = (const float*)d_in[11];
    const float* bn2   = (const float*)d_in[12];
    const float* e_wq  = (const float*)d_in[13];
    const float* e_wk  = (const float*)d_in[14];
    const float* e_wv  = (const float*)d_in[15];
    const float* e_wo  = (const float*)d_in[16];
    const float* e_wf1 = (const float*)d_in[17];
    const float* e_bf1 = (const float*)d_in[18];
    const float* e_wf2 = (const float*)d_in[19];
    const float* e_bf2 = (const float*)d_in[20];
    const float* w_pn  = (const float*)d_in[21];
    const float* w_fc  = (const float*)d_in[22];
    float* outp = (float*)d_out;

    // ---- compact workspace layout: 254,017,536 B total ----
    char* wsc = (char*)d_ws;
    float* h    = (float*)wsc;                       //      0 .. 83,886,080   (fp32 residual)
    u16*   hb   = (u16*)(wsc + 83886080);            //  +41,943,040
    u16*   qaob = (u16*)(wsc + 125829120);           //  +41,943,040  (qb, later aob)
    u16*   kb   = (u16*)(wsc + 167772160);           //  +41,943,040
    u16*   vt   = (u16*)(wsc + 209715200);           //  +41,943,040
    u16*   wT   = (u16*)(wsc + 251658240);           //   +2,097,152
    float* ubuf = (float*)(wsc + 253755392);         //     +262,144
    u16*   hidb = kb;  // overlays kb+vt (83,886,080 B; disjoint lifetime)

    prep_kernel<<<dim3(512, 12), 256, 0, stream>>>(e_wq, e_wk, e_wv, e_wo, e_wf1, e_wf2, wT);
    embed_kernel<<<dim3(GP, BB), 256, 0, stream>>>(obs, wi1, bi1, wi2, bi2,
                                                   wl1, bl1, wl2, bl2,
                                                   wn1, bn1, wn2, bn2, h, hb);
    const size_t WL = 524288;
    for (int l = 0; l < NL; l++) {
        u16* wqkvT = wT + l * WL;          // rows 0..767 (q,k,v)
        u16* woT   = wqkvT + 196608;
        u16* w1T   = wqkvT + 262144;
        u16* w2T   = wqkvT + 393216;
        const float* bf1 = e_bf1 + (size_t)l * FFH;
        const float* bf2 = e_bf2 + (size_t)l * EE;

        qkv_gemm<<<dim3(MT / 128, 6), 256, 0, stream>>>(hb, wqkvT, qaob, kb, vt);
        attn_core<<<dim3(GP / 32, BB), 256, 0, stream>>>(qaob, kb, vt, obs, qaob);
        gemmln_kernel<4, 256, 256, false><<<MT / 128, 512, 0, stream>>>(qaob, woT, nullptr, h, hb);
        ff1_gemm<<<dim3(MT / 128, 4), 256, 0, stream>>>(hb, w1T, bf1, hidb);
        gemmln_kernel<8, 512, 512, true><<<MT / 128, 512, 0, stream>>>(hidb, w2T, bf2, h, hb);
    }
    final1_kernel<<<BB, 256, 0, stream>>>(h, obs, w_fc, w_pn, ubuf);
    final2_kernel<<<BB, 128, 0, stream>>>(h, obs, ubuf, outp);
}

// Round 5
// 915.077 us; speedup vs baseline: 6.2237x; 1.0547x over previous
//
#include <hip/hip_runtime.h>
#include <math.h>

static constexpr int BB   = 256;   // batch
static constexpr int IHN  = 200;   // internal tokens
static constexpr int ILN  = 6;     // internal feature dim
static constexpr int LHN  = 100;   // leaf tokens
static constexpr int EE   = 256;   // embed dim
static constexpr int FFH  = 512;   // ff hidden
static constexpr int NL   = 2;     // layers
static constexpr int GG   = 301;   // real tokens
static constexpr int GP   = 320;   // padded tokens (10 x 32)
static constexpr int MT   = BB * GP;  // 81920 total token rows (640 x 128)

typedef unsigned short u16;
typedef short bf16x8 __attribute__((ext_vector_type(8)));
typedef float f32x4 __attribute__((ext_vector_type(4)));

#define MFMA(a, b, c) __builtin_amdgcn_mfma_f32_16x16x32_bf16((a), (b), (c), 0, 0, 0)

__device__ __forceinline__ u16 f2bf(float f) {
    union { float f; unsigned u; } v; v.f = f;
    unsigned r = v.u + 0x7FFFu + ((v.u >> 16) & 1u);
    return (u16)(r >> 16);
}

// ---------------- wave/block reduction helpers (wave = 64) ----------------
__device__ __forceinline__ float waveReduceSum(float v) {
    for (int o = 32; o > 0; o >>= 1) v += __shfl_down(v, o, 64);
    return v;
}
__device__ __forceinline__ float waveReduceMax(float v) {
    for (int o = 32; o > 0; o >>= 1) v = fmaxf(v, __shfl_down(v, o, 64));
    return v;
}
__device__ __forceinline__ float blockReduceSum(float v, float* red) {
    int lane = threadIdx.x & 63;
    int w    = threadIdx.x >> 6;
    int nw   = (blockDim.x + 63) >> 6;
    v = waveReduceSum(v);
    if (lane == 0) red[w] = v;
    __syncthreads();
    if (threadIdx.x < 64) {
        float x = (lane < nw) ? red[lane] : 0.0f;
        x = waveReduceSum(x);
        if (lane == 0) red[0] = x;
    }
    __syncthreads();
    float r = red[0];
    __syncthreads();
    return r;
}
__device__ __forceinline__ float blockReduceMax(float v, float* red) {
    int lane = threadIdx.x & 63;
    int w    = threadIdx.x >> 6;
    int nw   = (blockDim.x + 63) >> 6;
    v = waveReduceMax(v);
    if (lane == 0) red[w] = v;
    __syncthreads();
    if (threadIdx.x < 64) {
        float x = (lane < nw) ? red[lane] : -INFINITY;
        x = waveReduceMax(x);
        if (lane == 0) red[0] = x;
    }
    __syncthreads();
    float r = red[0];
    __syncthreads();
    return r;
}

// --------- staging: global -> LDS tile [rows][64] bf16, XOR-swizzled ---------
// LDS linear byte o: row = o>>7, colbyte = (o&127) ^ ((row&7)<<4).
// Pre-swizzle the global SOURCE so LDS dest stays linear (global_load_lds rule).
__device__ __forceinline__ void stage_swz(const u16* src, int strideShorts, int k0,
                                          u16* ldsTile, int nChunks, int wave,
                                          int nWaves, int lane)
{
    for (int c = wave; c < nChunks; c += nWaves) {
        int o = c * 1024 + lane * 16;
        int row = o >> 7;
        int cb = (o & 127) ^ ((row & 7) << 4);
        const u16* g = src + (size_t)row * strideShorts + k0 + (cb >> 1);
        __builtin_amdgcn_global_load_lds(
            (const __attribute__((address_space(1))) unsigned int*)g,
            (__attribute__((address_space(3))) unsigned int*)((char*)ldsTile + c * 1024),
            16, 0, 0);
    }
}

// swizzled LDS read of one bf16x8 fragment: logical (row, k-chunk kk, quarter q)
__device__ __forceinline__ bf16x8 lds_frag(const u16* tile, int row, int kk, int q)
{
    int cb = (kk * 64 + q * 16) ^ ((row & 7) << 4);
    return *(const bf16x8*)((const char*)tile + row * 128 + cb);
}

// ------------- prep: transpose encoder weights to bf16 [N][K] -------------
// per-layer (shorts): wqT(65536) wkT wvT woT  w1T[512][256]  w2T[256][512]
__global__ __launch_bounds__(256) void prep_kernel(
    const float* __restrict__ wq, const float* __restrict__ wk,
    const float* __restrict__ wv, const float* __restrict__ wo,
    const float* __restrict__ wf1, const float* __restrict__ wf2,
    u16* __restrict__ wT)
{
    int l = blockIdx.y / 6, m = blockIdx.y % 6;
    int idx = blockIdx.x * 256 + threadIdx.x;
    u16* dst = wT + (size_t)l * 524288;
    if (m < 4) {
        if (idx >= EE * EE) return;
        const float* src = (m == 0 ? wq : m == 1 ? wk : m == 2 ? wv : wo) + (size_t)l * EE * EE;
        int r = idx >> 8, c = idx & 255;
        dst[m * 65536 + idx] = f2bf(src[(size_t)c * EE + r]);
    } else if (m == 4) {
        if (idx >= FFH * EE) return;
        const float* src = wf1 + (size_t)l * EE * FFH;
        int r = idx >> 8, c = idx & 255;
        dst[262144 + idx] = f2bf(src[(size_t)c * FFH + r]);
    } else {
        if (idx >= EE * FFH) return;
        const float* src = wf2 + (size_t)l * FFH * EE;
        int r = idx >> 9, c = idx & 511;
        dst[393216 + idx] = f2bf(src[(size_t)c * EE + r]);
    }
}

// ---------------- embed: 3 small MLPs -> h (fp32) + hb (bf16) ----------------
__global__ __launch_bounds__(256) void embed_kernel(
    const float* __restrict__ obs,
    const float* __restrict__ wi1, const float* __restrict__ bi1,
    const float* __restrict__ wi2, const float* __restrict__ bi2,
    const float* __restrict__ wl1, const float* __restrict__ bl1,
    const float* __restrict__ wl2, const float* __restrict__ bl2,
    const float* __restrict__ wn1, const float* __restrict__ bn1,
    const float* __restrict__ wn2, const float* __restrict__ bn2,
    float* __restrict__ h, u16* __restrict__ hb)
{
    int g = blockIdx.x;
    int b = blockIdx.y;
    int t = threadIdx.x;
    size_t o = ((size_t)b * GP + g) * EE + t;
    if (g >= GG) { h[o] = 0.0f; hb[o] = 0; return; }

    const float* x = obs + ((size_t)b * GG + g) * 9;
    const float *w1, *b1, *w2, *b2;
    int ind;
    if (g < IHN)            { w1 = wi1; b1 = bi1; w2 = wi2; b2 = bi2; ind = ILN; }
    else if (g < IHN + LHN) { w1 = wl1; b1 = bl1; w2 = wl2; b2 = bl2; ind = 8;  }
    else                    { w1 = wn1; b1 = bn1; w2 = wn2; b2 = bn2; ind = 6;  }

    __shared__ float xs[8];
    __shared__ float hid[32];
    if (t < ind) xs[t] = x[t];
    __syncthreads();
    if (t < 32) {
        float a = b1[t];
        for (int i = 0; i < ind; i++) a += xs[i] * w1[i * 32 + t];
        hid[t] = (a > 0.0f) ? a : 0.01f * a;
    }
    __syncthreads();
    float a = b2[t];
    #pragma unroll
    for (int j = 0; j < 32; j++) a += hid[j] * w2[j * EE + t];
    h[o] = a; hb[o] = f2bf(a);
}

// --------- QKV GEMM: 128x128 tile, epilogue scatters Q/K rows + V^T ---------
__global__ __launch_bounds__(256) void qkv_gemm(
    const u16* __restrict__ hb, const u16* __restrict__ wqkvT,
    u16* __restrict__ qb, u16* __restrict__ kb, u16* __restrict__ vt)
{
    __shared__ __align__(16) u16 sA[128 * 64];
    __shared__ __align__(16) u16 sB[128 * 64];
    int tid = threadIdx.x, lane = tid & 63, w = tid >> 6;
    int wm = w >> 1, wn = w & 1;
    int lr = lane & 15, q = lane >> 4;
    int brow = blockIdx.x * 128;
    int bcol = blockIdx.y * 128;

    f32x4 acc[4][4];
    #pragma unroll
    for (int i = 0; i < 4; i++)
        #pragma unroll
        for (int j = 0; j < 4; j++) acc[i][j] = {0.0f, 0.0f, 0.0f, 0.0f};

    for (int ks = 0; ks < 4; ks++) {
        __syncthreads();
        stage_swz(hb + (size_t)brow * 256, 256, ks * 64, sA, 16, w, 4, lane);
        stage_swz(wqkvT + (size_t)bcol * 256, 256, ks * 64, sB, 16, w, 4, lane);
        __syncthreads();
        #pragma unroll
        for (int kk = 0; kk < 2; kk++) {
            bf16x8 a[4], b[4];
            #pragma unroll
            for (int i = 0; i < 4; i++) {
                a[i] = lds_frag(sA, wm * 64 + i * 16 + lr, kk, q);
                b[i] = lds_frag(sB, wn * 64 + i * 16 + lr, kk, q);
            }
            #pragma unroll
            for (int mi = 0; mi < 4; mi++)
                #pragma unroll
                for (int ni = 0; ni < 4; ni++)
                    acc[mi][ni] = MFMA(a[mi], b[ni], acc[mi][ni]);
        }
    }

    if (bcol < 512) {
        u16* dst = (bcol < 256) ? qb : kb;
        int cOff = bcol & 255;
        #pragma unroll
        for (int mi = 0; mi < 4; mi++)
            #pragma unroll
            for (int ni = 0; ni < 4; ni++) {
                int col = cOff + wn * 64 + ni * 16 + lr;
                #pragma unroll
                for (int j = 0; j < 4; j++) {
                    int rowG = brow + wm * 64 + mi * 16 + q * 4 + j;
                    dst[(size_t)rowG * 256 + col] = f2bf(acc[mi][ni][j]);
                }
            }
    } else {
        #pragma unroll
        for (int mi = 0; mi < 4; mi++) {
            int rowG0 = brow + wm * 64 + mi * 16 + q * 4;
            int b0 = rowG0 / GP;
            int g0 = rowG0 - b0 * GP;
            #pragma unroll
            for (int ni = 0; ni < 4; ni++) {
                int e = (bcol - 512) + wn * 64 + ni * 16 + lr;
                ushort4 u4;
                u4.x = f2bf(acc[mi][ni][0]);
                u4.y = f2bf(acc[mi][ni][1]);
                u4.z = f2bf(acc[mi][ni][2]);
                u4.w = f2bf(acc[mi][ni][3]);
                *(ushort4*)(vt + ((size_t)(b0 * EE + e)) * GP + g0) = u4;
            }
        }
    }
}

// --------- FF1 GEMM: 128x128 tile, epilogue bias+relu -> hidb bf16 ---------
__global__ __launch_bounds__(256) void ff1_gemm(
    const u16* __restrict__ hb, const u16* __restrict__ w1T,
    const float* __restrict__ bf1, u16* __restrict__ hidb)
{
    __shared__ __align__(16) u16 sA[128 * 64];
    __shared__ __align__(16) u16 sB[128 * 64];
    int tid = threadIdx.x, lane = tid & 63, w = tid >> 6;
    int wm = w >> 1, wn = w & 1;
    int lr = lane & 15, q = lane >> 4;
    int brow = blockIdx.x * 128;
    int bcol = blockIdx.y * 128;

    f32x4 acc[4][4];
    #pragma unroll
    for (int i = 0; i < 4; i++)
        #pragma unroll
        for (int j = 0; j < 4; j++) acc[i][j] = {0.0f, 0.0f, 0.0f, 0.0f};

    for (int ks = 0; ks < 4; ks++) {
        __syncthreads();
        stage_swz(hb + (size_t)brow * 256, 256, ks * 64, sA, 16, w, 4, lane);
        stage_swz(w1T + (size_t)bcol * 256, 256, ks * 64, sB, 16, w, 4, lane);
        __syncthreads();
        #pragma unroll
        for (int kk = 0; kk < 2; kk++) {
            bf16x8 a[4], b[4];
            #pragma unroll
            for (int i = 0; i < 4; i++) {
                a[i] = lds_frag(sA, wm * 64 + i * 16 + lr, kk, q);
                b[i] = lds_frag(sB, wn * 64 + i * 16 + lr, kk, q);
            }
            #pragma unroll
            for (int mi = 0; mi < 4; mi++)
                #pragma unroll
                for (int ni = 0; ni < 4; ni++)
                    acc[mi][ni] = MFMA(a[mi], b[ni], acc[mi][ni]);
        }
    }

    #pragma unroll
    for (int ni = 0; ni < 4; ni++) {
        int col = bcol + wn * 64 + ni * 16 + lr;
        float bias = bf1[col];
        #pragma unroll
        for (int mi = 0; mi < 4; mi++)
            #pragma unroll
            for (int j = 0; j < 4; j++) {
                int rowG = brow + wm * 64 + mi * 16 + q * 4 + j;
                float v = acc[mi][ni][j] + bias;
                hidb[(size_t)rowG * 512 + col] = f2bf(fmaxf(v, 0.0f));
            }
    }
}

// ---- GEMM + residual + LayerNorm: BM=128, BN=256(full row), 8 waves ----
template<int KSTEPS, int ASTR, int BSTR, bool HASB>
__global__ __launch_bounds__(512) void gemmln_kernel(
    const u16* __restrict__ A, const u16* __restrict__ Bw,
    const float* __restrict__ bias, float* __restrict__ h, u16* __restrict__ hb)
{
    __shared__ __align__(16) u16 sA[128 * 64];   // 16 KB
    __shared__ __align__(16) u16 sB[256 * 64];   // 32 KB
    int tid = threadIdx.x, lane = tid & 63, w = tid >> 6;
    int wm = w >> 2, wn = w & 3;
    int lr = lane & 15, q = lane >> 4;
    int brow = blockIdx.x * 128;

    f32x4 acc[4][4];
    #pragma unroll
    for (int i = 0; i < 4; i++)
        #pragma unroll
        for (int j = 0; j < 4; j++) acc[i][j] = {0.0f, 0.0f, 0.0f, 0.0f};

    for (int ks = 0; ks < KSTEPS; ks++) {
        __syncthreads();
        stage_swz(A + (size_t)brow * ASTR, ASTR, ks * 64, sA, 16, w, 8, lane);
        stage_swz(Bw, BSTR, ks * 64, sB, 32, w, 8, lane);
        __syncthreads();
        #pragma unroll
        for (int kk = 0; kk < 2; kk++) {
            bf16x8 a[4], b[4];
            #pragma unroll
            for (int i = 0; i < 4; i++) {
                a[i] = lds_frag(sA, wm * 64 + i * 16 + lr, kk, q);
                b[i] = lds_frag(sB, wn * 64 + i * 16 + lr, kk, q);
            }
            #pragma unroll
            for (int mi = 0; mi < 4; mi++)
                #pragma unroll
                for (int ni = 0; ni < 4; ni++)
                    acc[mi][ni] = MFMA(a[mi], b[ni], acc[mi][ni]);
        }
    }

    __syncthreads();                     // LDS reads done -> overlay sPart
    float* sPart = (float*)sA;           // [4 wn][128 row][2]

    // vals = acc + bias + residual (in place)
    #pragma unroll
    for (int ni = 0; ni < 4; ni++) {
        int col = wn * 64 + ni * 16 + lr;
        float bv = HASB ? bias[col] : 0.0f;
        #pragma unroll
        for (int mi = 0; mi < 4; mi++)
            #pragma unroll
            for (int j = 0; j < 4; j++) {
                int rowG = brow + wm * 64 + mi * 16 + q * 4 + j;
                acc[mi][ni][j] += bv + h[(size_t)rowG * 256 + col];
            }
    }
    // per-row partial sums (this wave's 64-col stripe)
    #pragma unroll
    for (int mi = 0; mi < 4; mi++)
        #pragma unroll
        for (int j = 0; j < 4; j++) {
            float s1 = 0.0f, s2 = 0.0f;
            #pragma unroll
            for (int ni = 0; ni < 4; ni++) {
                float v = acc[mi][ni][j];
                s1 += v; s2 += v * v;
            }
            s1 += __shfl_xor(s1, 1); s2 += __shfl_xor(s2, 1);
            s1 += __shfl_xor(s1, 2); s2 += __shfl_xor(s2, 2);
            s1 += __shfl_xor(s1, 4); s2 += __shfl_xor(s2, 4);
            s1 += __shfl_xor(s1, 8); s2 += __shfl_xor(s2, 8);
            if (lr == 0) {
                int lrow = wm * 64 + mi * 16 + q * 4 + j;
                sPart[(wn * 128 + lrow) * 2 + 0] = s1;
                sPart[(wn * 128 + lrow) * 2 + 1] = s2;
            }
        }
    __syncthreads();

    #pragma unroll
    for (int mi = 0; mi < 4; mi++)
        #pragma unroll
        for (int j = 0; j < 4; j++) {
            int lrow = wm * 64 + mi * 16 + q * 4 + j;
            float s1 = sPart[lrow * 2] + sPart[(128 + lrow) * 2] +
                       sPart[(256 + lrow) * 2] + sPart[(384 + lrow) * 2];
            float s2 = sPart[lrow * 2 + 1] + sPart[(128 + lrow) * 2 + 1] +
                       sPart[(256 + lrow) * 2 + 1] + sPart[(384 + lrow) * 2 + 1];
            float mean = s1 * (1.0f / 256.0f);
            float var  = s2 * (1.0f / 256.0f) - mean * mean;
            float rstd = rsqrtf(var + 1e-5f);
            int rowG = brow + lrow;
            #pragma unroll
            for (int ni = 0; ni < 4; ni++) {
                int col = wn * 64 + ni * 16 + lr;
                float v = (acc[mi][ni][j] - mean) * rstd;
                size_t o = (size_t)rowG * 256 + col;
                h[o] = v; hb[o] = f2bf(v);
            }
        }
}

// ------- attention core: S=QK^T, softmax(in-reg), PV -> aob -------
// 64 q-rows/block, 8 waves, XCD-bijective swizzle: all 5 tiles of a batch
// land on one XCD so K/V (320 KB/batch) is fetched from HBM once and
// served from that XCD's L2 afterwards.
// NOTE: aob may alias qb (qb reads happen before the P barriers; aob writes
// after; each block only touches its own 64 rows of both).
__global__ __launch_bounds__(512) void attn_core(
    const u16* __restrict__ qb, const u16* __restrict__ kb,
    const u16* __restrict__ vt, const float* __restrict__ obs,
    u16* __restrict__ aob)
{
    __shared__ __align__(16) u16 sP[64][328];   // 41,984 B
    __shared__ float sBias[320];
    __shared__ float sPm[4][64], sPs[4][64];

    int id = blockIdx.x;                 // 1280 blocks
    int xcd = id & 7, jj = id >> 3;      // jj in [0,160)
    int tile = jj % 5, bgrp = jj / 5;    // bgrp in [0,32)
    int b = xcd + 8 * bgrp;              // bijective batch in [0,256)
    int t0 = tile * 64;

    int tid = threadIdx.x, w = tid >> 6, lane = tid & 63;
    int mh = w >> 2, jq = w & 3;         // row-half, j-quarter
    int lr = lane & 15, q = lane >> 4, lk = q * 8;

    if (tid < 320) {
        float msk = (tid < GG) ? obs[((size_t)b * GG + tid) * 9 + 8] : 0.0f;
        sBias[tid] = (1.0f - msk) * -1e9f;
    }
    __syncthreads();

    // scores: rows [mh*32, +32) x j in [jq*80, +80)
    f32x4 sacc[2][5];
    #pragma unroll
    for (int mi = 0; mi < 2; mi++)
        #pragma unroll
        for (int jt = 0; jt < 5; jt++) sacc[mi][jt] = {0.0f, 0.0f, 0.0f, 0.0f};

    for (int k = 0; k < 8; k++) {
        bf16x8 a0 = *(const bf16x8*)(qb + ((size_t)(b * GP + t0 + mh * 32 + lr)) * 256 + k * 32 + lk);
        bf16x8 a1 = *(const bf16x8*)(qb + ((size_t)(b * GP + t0 + mh * 32 + 16 + lr)) * 256 + k * 32 + lk);
        #pragma unroll
        for (int jt = 0; jt < 5; jt++) {
            int j = jq * 80 + jt * 16 + lr;
            bf16x8 bb = *(const bf16x8*)(kb + ((size_t)(b * GP + j)) * 256 + k * 32 + lk);
            sacc[0][jt] = MFMA(a0, bb, sacc[0][jt]);
            sacc[1][jt] = MFMA(a1, bb, sacc[1][jt]);
        }
    }
    #pragma unroll
    for (int jt = 0; jt < 5; jt++) {
        float bia = sBias[jq * 80 + jt * 16 + lr];
        #pragma unroll
        for (int mi = 0; mi < 2; mi++)
            #pragma unroll
            for (int r = 0; r < 4; r++)
                sacc[mi][jt][r] = sacc[mi][jt][r] * 0.0625f + bia;
    }
    // partial row max over this wave's j range
    #pragma unroll
    for (int mi = 0; mi < 2; mi++)
        #pragma unroll
        for (int r = 0; r < 4; r++) {
            float mx = -1e30f;
            #pragma unroll
            for (int jt = 0; jt < 5; jt++) mx = fmaxf(mx, sacc[mi][jt][r]);
            mx = fmaxf(mx, __shfl_xor(mx, 1));
            mx = fmaxf(mx, __shfl_xor(mx, 2));
            mx = fmaxf(mx, __shfl_xor(mx, 4));
            mx = fmaxf(mx, __shfl_xor(mx, 8));
            if (lr == 0) sPm[jq][mh * 32 + mi * 16 + q * 4 + r] = mx;
        }
    __syncthreads();
    #pragma unroll
    for (int mi = 0; mi < 2; mi++)
        #pragma unroll
        for (int r = 0; r < 4; r++) {
            int row = mh * 32 + mi * 16 + q * 4 + r;
            float rm = fmaxf(fmaxf(sPm[0][row], sPm[1][row]), fmaxf(sPm[2][row], sPm[3][row]));
            float ss = 0.0f;
            #pragma unroll
            for (int jt = 0; jt < 5; jt++) {
                float e = __expf(sacc[mi][jt][r] - rm);
                sacc[mi][jt][r] = e;
                ss += e;
            }
            ss += __shfl_xor(ss, 1);
            ss += __shfl_xor(ss, 2);
            ss += __shfl_xor(ss, 4);
            ss += __shfl_xor(ss, 8);
            if (lr == 0) sPs[jq][row] = ss;
        }
    __syncthreads();
    #pragma unroll
    for (int mi = 0; mi < 2; mi++)
        #pragma unroll
        for (int r = 0; r < 4; r++) {
            int row = mh * 32 + mi * 16 + q * 4 + r;
            float inv = 1.0f / (sPs[0][row] + sPs[1][row] + sPs[2][row] + sPs[3][row]);
            #pragma unroll
            for (int jt = 0; jt < 5; jt++)
                sP[row][jq * 80 + jt * 16 + lr] = f2bf(sacc[mi][jt][r] * inv);
        }
    __syncthreads();

    // PV: rows [mh*32, +32) x e in [jq*64, +64)
    f32x4 oacc[2][4];
    #pragma unroll
    for (int mi = 0; mi < 2; mi++)
        #pragma unroll
        for (int ni = 0; ni < 4; ni++) oacc[mi][ni] = {0.0f, 0.0f, 0.0f, 0.0f};

    for (int ks = 0; ks < 10; ks++) {
        bf16x8 a0 = *(const bf16x8*)(&sP[mh * 32 + lr][ks * 32 + lk]);
        bf16x8 a1 = *(const bf16x8*)(&sP[mh * 32 + 16 + lr][ks * 32 + lk]);
        #pragma unroll
        for (int ni = 0; ni < 4; ni++) {
            int e = jq * 64 + ni * 16 + lr;
            bf16x8 bb = *(const bf16x8*)(vt + ((size_t)(b * EE + e)) * GP + ks * 32 + lk);
            oacc[0][ni] = MFMA(a0, bb, oacc[0][ni]);
            oacc[1][ni] = MFMA(a1, bb, oacc[1][ni]);
        }
    }
    #pragma unroll
    for (int mi = 0; mi < 2; mi++)
        #pragma unroll
        for (int ni = 0; ni < 4; ni++) {
            int col = jq * 64 + ni * 16 + lr;
            #pragma unroll
            for (int r = 0; r < 4; r++) {
                int row = mh * 32 + mi * 16 + q * 4 + r;
                aob[((size_t)(b * GP + t0 + row)) * 256 + col] = f2bf(oacc[mi][ni][r]);
            }
        }
}

// ------------- head part 1: graph embed -> fixed context -> u[b] -------------
__global__ __launch_bounds__(256) void final1_kernel(
    const float* __restrict__ h, const float* __restrict__ obs,
    const float* __restrict__ w_fc, const float* __restrict__ w_pn,
    float* __restrict__ u)
{
    int b = blockIdx.x;
    int t = threadIdx.x;
    __shared__ float ges[EE];
    __shared__ float fcs[EE];

    float acc = 0.0f, vlen = 0.0f;
    for (int g = 0; g < GG; g++) {
        float m = obs[((size_t)b * GG + g) * 9 + 8];
        vlen += m;
        acc += h[((size_t)b * GP + g) * EE + t] * m;
    }
    ges[t] = acc / vlen;
    __syncthreads();

    float fc = 0.0f;
    for (int kk = 0; kk < EE; kk++) fc += ges[kk] * w_fc[kk * EE + t];
    fcs[t] = fc;
    __syncthreads();

    const float4* wp = reinterpret_cast<const float4*>(w_pn + (size_t)t * 3 * EE);
    float ua = 0.0f;
    for (int kk = 0; kk < EE / 4; kk++) {
        float4 w = wp[kk];
        ua += w.x * fcs[kk * 4] + w.y * fcs[kk * 4 + 1] +
              w.z * fcs[kk * 4 + 2] + w.w * fcs[kk * 4 + 3];
    }
    u[(size_t)b * EE + t] = ua;
}

// ------------- head part 2: compat -> tanh clip -> masked softmax -------------
__global__ __launch_bounds__(128) void final2_kernel(
    const float* __restrict__ h, const float* __restrict__ obs,
    const float* __restrict__ u, float* __restrict__ out)
{
    int b = blockIdx.x;
    int t = threadIdx.x;
    __shared__ float us[EE];
    __shared__ float red[8];
    us[t]       = u[(size_t)b * EE + t];
    us[t + 128] = u[(size_t)b * EE + t + 128];
    __syncthreads();

    float logit = -INFINITY;
    float m = 0.0f;
    if (t < LHN) {
        int g = IHN + t;
        m = obs[((size_t)b * GG + g) * 9 + 8];
        const float4* hr = reinterpret_cast<const float4*>(h + ((size_t)b * GP + g) * EE);
        float c = 0.0f;
        for (int kk = 0; kk < EE / 4; kk++) {
            float4 hv = hr[kk];
            c += hv.x * us[kk * 4] + hv.y * us[kk * 4 + 1] +
                 hv.z * us[kk * 4 + 2] + hv.w * us[kk * 4 + 3];
        }
        c *= m;
        c *= 0.0625f;
        logit = tanhf(c) * 10.0f;
    }
    float bm = blockReduceMax(logit, red);
    float e  = (t < LHN) ? __expf(logit - bm) : 0.0f;
    float bs = blockReduceSum(e, red);
    float p  = e / bs;
    float masked = (t < LHN) ? (p * m + 1e-20f) : 0.0f;
    float bs2 = blockReduceSum(masked, red);
    if (t < LHN) out[(size_t)b * LHN + t] = masked / bs2;
}

extern "C" void kernel_launch(void* const* d_in, const int* in_sizes, int n_in,
                              void* d_out, int out_size, void* d_ws, size_t ws_size,
                              hipStream_t stream) {
    const float* obs   = (const float*)d_in[0];
    const float* wi1   = (const float*)d_in[1];
    const float* bi1   = (const float*)d_in[2];
    const float* wi2   = (const float*)d_in[3];
    const float* bi2   = (const float*)d_in[4];
    const float* wl1   = (const float*)d_in[5];
    const float* bl1   = (const float*)d_in[6];
    const float* wl2   = (const float*)d_in[7];
    const float* bl2   = (const float*)d_in[8];
    const float* wn1   = (const float*)d_in[9];
    const float* bn1   = (const float*)d_in[10];
    const float* wn2   = (const float*)d_in[11];
    const float* bn2   = (const float*)d_in[12];
    const float* e_wq  = (const float*)d_in[13];
    const float* e_wk  = (const float*)d_in[14];
    const float* e_wv  = (const float*)d_in[15];
    const float* e_wo  = (const float*)d_in[16];
    const float* e_wf1 = (const float*)d_in[17];
    const float* e_bf1 = (const float*)d_in[18];
    const float* e_wf2 = (const float*)d_in[19];
    const float* e_bf2 = (const float*)d_in[20];
    const float* w_pn  = (const float*)d_in[21];
    const float* w_fc  = (const float*)d_in[22];
    float* outp = (float*)d_out;

    // ---- compact workspace layout: 254,017,536 B total ----
    char* wsc = (char*)d_ws;
    float* h    = (float*)wsc;                       //      0 .. 83,886,080   (fp32 residual)
    u16*   hb   = (u16*)(wsc + 83886080);            //  +41,943,040
    u16*   qaob = (u16*)(wsc + 125829120);           //  +41,943,040  (qb, later aob)
    u16*   kb   = (u16*)(wsc + 167772160);           //  +41,943,040
    u16*   vt   = (u16*)(wsc + 209715200);           //  +41,943,040
    u16*   wT   = (u16*)(wsc + 251658240);           //   +2,097,152
    float* ubuf = (float*)(wsc + 253755392);         //     +262,144
    u16*   hidb = kb;  // overlays kb+vt (83,886,080 B; disjoint lifetime)

    prep_kernel<<<dim3(512, 12), 256, 0, stream>>>(e_wq, e_wk, e_wv, e_wo, e_wf1, e_wf2, wT);
    embed_kernel<<<dim3(GP, BB), 256, 0, stream>>>(obs, wi1, bi1, wi2, bi2,
                                                   wl1, bl1, wl2, bl2,
                                                   wn1, bn1, wn2, bn2, h, hb);
    const size_t WL = 524288;
    for (int l = 0; l < NL; l++) {
        u16* wqkvT = wT + l * WL;          // rows 0..767 (q,k,v)
        u16* woT   = wqkvT + 196608;
        u16* w1T   = wqkvT + 262144;
        u16* w2T   = wqkvT + 393216;
        const float* bf1 = e_bf1 + (size_t)l * FFH;
        const float* bf2 = e_bf2 + (size_t)l * EE;

        qkv_gemm<<<dim3(MT / 128, 6), 256, 0, stream>>>(hb, wqkvT, qaob, kb, vt);
        attn_core<<<1280, 512, 0, stream>>>(qaob, kb, vt, obs, qaob);
        gemmln_kernel<4, 256, 256, false><<<MT / 128, 512, 0, stream>>>(qaob, woT, nullptr, h, hb);
        ff1_gemm<<<dim3(MT / 128, 4), 256, 0, stream>>>(hb, w1T, bf1, hidb);
        gemmln_kernel<8, 512, 512, true><<<MT / 128, 512, 0, stream>>>(hidb, w2T, bf2, h, hb);
    }
    final1_kernel<<<BB, 256, 0, stream>>>(h, obs, w_fc, w_pn, ubuf);
    final2_kernel<<<BB, 128, 0, stream>>>(h, obs, ubuf, outp);
}

// Round 6
// 860.631 us; speedup vs baseline: 6.6175x; 1.0633x over previous
//
#include <hip/hip_runtime.h>
#include <math.h>

static constexpr int BB   = 256;   // batch
static constexpr int IHN  = 200;   // internal tokens
static constexpr int ILN  = 6;     // internal feature dim
static constexpr int LHN  = 100;   // leaf tokens
static constexpr int EE   = 256;   // embed dim
static constexpr int FFH  = 512;   // ff hidden
static constexpr int NL   = 2;     // layers
static constexpr int GG   = 301;   // real tokens
static constexpr int GP   = 320;   // padded tokens (10 x 32)
static constexpr int MT   = BB * GP;  // 81920 total token rows (640 x 128)

typedef unsigned short u16;
typedef short bf16x8 __attribute__((ext_vector_type(8)));
typedef float f32x4 __attribute__((ext_vector_type(4)));

#define MFMA(a, b, c) __builtin_amdgcn_mfma_f32_16x16x32_bf16((a), (b), (c), 0, 0, 0)

__device__ __forceinline__ u16 f2bf(float f) {
    union { float f; unsigned u; } v; v.f = f;
    unsigned r = v.u + 0x7FFFu + ((v.u >> 16) & 1u);
    return (u16)(r >> 16);
}

// ---------------- wave/block reduction helpers (wave = 64) ----------------
__device__ __forceinline__ float waveReduceSum(float v) {
    for (int o = 32; o > 0; o >>= 1) v += __shfl_down(v, o, 64);
    return v;
}
__device__ __forceinline__ float waveReduceMax(float v) {
    for (int o = 32; o > 0; o >>= 1) v = fmaxf(v, __shfl_down(v, o, 64));
    return v;
}
__device__ __forceinline__ float blockReduceSum(float v, float* red) {
    int lane = threadIdx.x & 63;
    int w    = threadIdx.x >> 6;
    int nw   = (blockDim.x + 63) >> 6;
    v = waveReduceSum(v);
    if (lane == 0) red[w] = v;
    __syncthreads();
    if (threadIdx.x < 64) {
        float x = (lane < nw) ? red[lane] : 0.0f;
        x = waveReduceSum(x);
        if (lane == 0) red[0] = x;
    }
    __syncthreads();
    float r = red[0];
    __syncthreads();
    return r;
}
__device__ __forceinline__ float blockReduceMax(float v, float* red) {
    int lane = threadIdx.x & 63;
    int w    = threadIdx.x >> 6;
    int nw   = (blockDim.x + 63) >> 6;
    v = waveReduceMax(v);
    if (lane == 0) red[w] = v;
    __syncthreads();
    if (threadIdx.x < 64) {
        float x = (lane < nw) ? red[lane] : -INFINITY;
        x = waveReduceMax(x);
        if (lane == 0) red[0] = x;
    }
    __syncthreads();
    float r = red[0];
    __syncthreads();
    return r;
}

// --------- staging: global -> LDS tile [rows][64] bf16, XOR-swizzled ---------
__device__ __forceinline__ void stage_swz(const u16* src, int strideShorts, int k0,
                                          u16* ldsTile, int nChunks, int wave,
                                          int nWaves, int lane)
{
    for (int c = wave; c < nChunks; c += nWaves) {
        int o = c * 1024 + lane * 16;
        int row = o >> 7;
        int cb = (o & 127) ^ ((row & 7) << 4);
        const u16* g = src + (size_t)row * strideShorts + k0 + (cb >> 1);
        __builtin_amdgcn_global_load_lds(
            (const __attribute__((address_space(1))) unsigned int*)g,
            (__attribute__((address_space(3))) unsigned int*)((char*)ldsTile + c * 1024),
            16, 0, 0);
    }
}

__device__ __forceinline__ bf16x8 lds_frag(const u16* tile, int row, int kk, int q)
{
    int cb = (kk * 64 + q * 16) ^ ((row & 7) << 4);
    return *(const bf16x8*)((const char*)tile + row * 128 + cb);
}

// ------------- prep: transpose encoder weights to bf16 [N][K] -------------
__global__ __launch_bounds__(256) void prep_kernel(
    const float* __restrict__ wq, const float* __restrict__ wk,
    const float* __restrict__ wv, const float* __restrict__ wo,
    const float* __restrict__ wf1, const float* __restrict__ wf2,
    u16* __restrict__ wT)
{
    int l = blockIdx.y / 6, m = blockIdx.y % 6;
    int idx = blockIdx.x * 256 + threadIdx.x;
    u16* dst = wT + (size_t)l * 524288;
    if (m < 4) {
        if (idx >= EE * EE) return;
        const float* src = (m == 0 ? wq : m == 1 ? wk : m == 2 ? wv : wo) + (size_t)l * EE * EE;
        int r = idx >> 8, c = idx & 255;
        dst[m * 65536 + idx] = f2bf(src[(size_t)c * EE + r]);
    } else if (m == 4) {
        if (idx >= FFH * EE) return;
        const float* src = wf1 + (size_t)l * EE * FFH;
        int r = idx >> 8, c = idx & 255;
        dst[262144 + idx] = f2bf(src[(size_t)c * FFH + r]);
    } else {
        if (idx >= EE * FFH) return;
        const float* src = wf2 + (size_t)l * FFH * EE;
        int r = idx >> 9, c = idx & 511;
        dst[393216 + idx] = f2bf(src[(size_t)c * EE + r]);
    }
}

// ---------- embed (segment version): 32 tokens/block, w2 col in regs ----------
template<int IND, int SEG, int G0>
__global__ __launch_bounds__(256) void embed_seg(
    const float* __restrict__ obs,
    const float* __restrict__ w1, const float* __restrict__ b1,
    const float* __restrict__ w2, const float* __restrict__ b2,
    float* __restrict__ h, u16* __restrict__ hb)
{
    __shared__ float xs[32][9];
    __shared__ float hid[32][33];
    int t = threadIdx.x;
    int fi0 = blockIdx.x * 32;

    // load obs rows for 32 tokens (288 floats)
    for (int p = t; p < 32 * 9; p += 256) {
        int tok = p / 9, f = p % 9;
        int fi = fi0 + tok;
        int b = fi / SEG, g = G0 + fi % SEG;
        xs[tok][f] = obs[((size_t)b * GG + g) * 9 + f];
    }
    __syncthreads();

    // hidden layer: 32 tokens x 32 hid = 1024 outputs, 4 per thread
    #pragma unroll
    for (int p = 0; p < 4; p++) {
        int idx = p * 256 + t;
        int tok = idx >> 5, hcol = idx & 31;
        float a = b1[hcol];
        #pragma unroll
        for (int i = 0; i < IND; i++) a += xs[tok][i] * w1[i * 32 + hcol];
        hid[tok][hcol] = (a > 0.0f) ? a : 0.01f * a;   // leaky_relu 0.01
    }
    __syncthreads();

    // output layer: thread owns column t; w2 column cached in registers
    float w2c[32];
    #pragma unroll
    for (int j = 0; j < 32; j++) w2c[j] = w2[j * EE + t];
    float bb = b2[t];
    for (int tok = 0; tok < 32; tok++) {
        int fi = fi0 + tok;
        int b = fi / SEG, g = G0 + fi % SEG;
        float a = bb;
        #pragma unroll
        for (int j = 0; j < 32; j++) a += hid[tok][j] * w2c[j];
        size_t o = ((size_t)b * GP + g) * EE + t;
        h[o] = a; hb[o] = f2bf(a);
    }
}

// zero the pad rows g in [GG, GP)
__global__ __launch_bounds__(256) void pad_kernel(float* __restrict__ h, u16* __restrict__ hb)
{
    int b = blockIdx.x, t = threadIdx.x;
    for (int g = GG; g < GP; g++) {
        size_t o = ((size_t)b * GP + g) * EE + t;
        h[o] = 0.0f; hb[o] = 0;
    }
}

// --------- QKV GEMM: 128x128 tile, epilogue scatters Q/K rows + V^T ---------
__global__ __launch_bounds__(256) void qkv_gemm(
    const u16* __restrict__ hb, const u16* __restrict__ wqkvT,
    u16* __restrict__ qb, u16* __restrict__ kb, u16* __restrict__ vt)
{
    __shared__ __align__(16) u16 sA[128 * 64];
    __shared__ __align__(16) u16 sB[128 * 64];
    int tid = threadIdx.x, lane = tid & 63, w = tid >> 6;
    int wm = w >> 1, wn = w & 1;
    int lr = lane & 15, q = lane >> 4;
    int brow = blockIdx.x * 128;
    int bcol = blockIdx.y * 128;

    f32x4 acc[4][4];
    #pragma unroll
    for (int i = 0; i < 4; i++)
        #pragma unroll
        for (int j = 0; j < 4; j++) acc[i][j] = {0.0f, 0.0f, 0.0f, 0.0f};

    for (int ks = 0; ks < 4; ks++) {
        __syncthreads();
        stage_swz(hb + (size_t)brow * 256, 256, ks * 64, sA, 16, w, 4, lane);
        stage_swz(wqkvT + (size_t)bcol * 256, 256, ks * 64, sB, 16, w, 4, lane);
        __syncthreads();
        #pragma unroll
        for (int kk = 0; kk < 2; kk++) {
            bf16x8 a[4], b[4];
            #pragma unroll
            for (int i = 0; i < 4; i++) {
                a[i] = lds_frag(sA, wm * 64 + i * 16 + lr, kk, q);
                b[i] = lds_frag(sB, wn * 64 + i * 16 + lr, kk, q);
            }
            #pragma unroll
            for (int mi = 0; mi < 4; mi++)
                #pragma unroll
                for (int ni = 0; ni < 4; ni++)
                    acc[mi][ni] = MFMA(a[mi], b[ni], acc[mi][ni]);
        }
    }

    if (bcol < 512) {
        u16* dst = (bcol < 256) ? qb : kb;
        int cOff = bcol & 255;
        #pragma unroll
        for (int mi = 0; mi < 4; mi++)
            #pragma unroll
            for (int ni = 0; ni < 4; ni++) {
                int col = cOff + wn * 64 + ni * 16 + lr;
                #pragma unroll
                for (int j = 0; j < 4; j++) {
                    int rowG = brow + wm * 64 + mi * 16 + q * 4 + j;
                    dst[(size_t)rowG * 256 + col] = f2bf(acc[mi][ni][j]);
                }
            }
    } else {
        #pragma unroll
        for (int mi = 0; mi < 4; mi++) {
            int rowG0 = brow + wm * 64 + mi * 16 + q * 4;
            int b0 = rowG0 / GP;
            int g0 = rowG0 - b0 * GP;
            #pragma unroll
            for (int ni = 0; ni < 4; ni++) {
                int e = (bcol - 512) + wn * 64 + ni * 16 + lr;
                ushort4 u4;
                u4.x = f2bf(acc[mi][ni][0]);
                u4.y = f2bf(acc[mi][ni][1]);
                u4.z = f2bf(acc[mi][ni][2]);
                u4.w = f2bf(acc[mi][ni][3]);
                *(ushort4*)(vt + ((size_t)(b0 * EE + e)) * GP + g0) = u4;
            }
        }
    }
}

// --------- FF1 GEMM: 128x128 tile, epilogue bias+relu -> hidb bf16 ---------
__global__ __launch_bounds__(256) void ff1_gemm(
    const u16* __restrict__ hb, const u16* __restrict__ w1T,
    const float* __restrict__ bf1, u16* __restrict__ hidb)
{
    __shared__ __align__(16) u16 sA[128 * 64];
    __shared__ __align__(16) u16 sB[128 * 64];
    int tid = threadIdx.x, lane = tid & 63, w = tid >> 6;
    int wm = w >> 1, wn = w & 1;
    int lr = lane & 15, q = lane >> 4;
    int brow = blockIdx.x * 128;
    int bcol = blockIdx.y * 128;

    f32x4 acc[4][4];
    #pragma unroll
    for (int i = 0; i < 4; i++)
        #pragma unroll
        for (int j = 0; j < 4; j++) acc[i][j] = {0.0f, 0.0f, 0.0f, 0.0f};

    for (int ks = 0; ks < 4; ks++) {
        __syncthreads();
        stage_swz(hb + (size_t)brow * 256, 256, ks * 64, sA, 16, w, 4, lane);
        stage_swz(w1T + (size_t)bcol * 256, 256, ks * 64, sB, 16, w, 4, lane);
        __syncthreads();
        #pragma unroll
        for (int kk = 0; kk < 2; kk++) {
            bf16x8 a[4], b[4];
            #pragma unroll
            for (int i = 0; i < 4; i++) {
                a[i] = lds_frag(sA, wm * 64 + i * 16 + lr, kk, q);
                b[i] = lds_frag(sB, wn * 64 + i * 16 + lr, kk, q);
            }
            #pragma unroll
            for (int mi = 0; mi < 4; mi++)
                #pragma unroll
                for (int ni = 0; ni < 4; ni++)
                    acc[mi][ni] = MFMA(a[mi], b[ni], acc[mi][ni]);
        }
    }

    #pragma unroll
    for (int ni = 0; ni < 4; ni++) {
        int col = bcol + wn * 64 + ni * 16 + lr;
        float bias = bf1[col];
        #pragma unroll
        for (int mi = 0; mi < 4; mi++)
            #pragma unroll
            for (int j = 0; j < 4; j++) {
                int rowG = brow + wm * 64 + mi * 16 + q * 4 + j;
                float v = acc[mi][ni][j] + bias;
                hidb[(size_t)rowG * 512 + col] = f2bf(fmaxf(v, 0.0f));
            }
    }
}

// ---- GEMM + residual + LayerNorm: BM=128, BN=256(full row), 8 waves ----
template<int KSTEPS, int ASTR, int BSTR, bool HASB>
__global__ __launch_bounds__(512) void gemmln_kernel(
    const u16* __restrict__ A, const u16* __restrict__ Bw,
    const float* __restrict__ bias, float* __restrict__ h, u16* __restrict__ hb)
{
    __shared__ __align__(16) u16 sA[128 * 64];   // 16 KB
    __shared__ __align__(16) u16 sB[256 * 64];   // 32 KB
    int tid = threadIdx.x, lane = tid & 63, w = tid >> 6;
    int wm = w >> 2, wn = w & 3;
    int lr = lane & 15, q = lane >> 4;
    int brow = blockIdx.x * 128;

    f32x4 acc[4][4];
    #pragma unroll
    for (int i = 0; i < 4; i++)
        #pragma unroll
        for (int j = 0; j < 4; j++) acc[i][j] = {0.0f, 0.0f, 0.0f, 0.0f};

    for (int ks = 0; ks < KSTEPS; ks++) {
        __syncthreads();
        stage_swz(A + (size_t)brow * ASTR, ASTR, ks * 64, sA, 16, w, 8, lane);
        stage_swz(Bw, BSTR, ks * 64, sB, 32, w, 8, lane);
        __syncthreads();
        #pragma unroll
        for (int kk = 0; kk < 2; kk++) {
            bf16x8 a[4], b[4];
            #pragma unroll
            for (int i = 0; i < 4; i++) {
                a[i] = lds_frag(sA, wm * 64 + i * 16 + lr, kk, q);
                b[i] = lds_frag(sB, wn * 64 + i * 16 + lr, kk, q);
            }
            #pragma unroll
            for (int mi = 0; mi < 4; mi++)
                #pragma unroll
                for (int ni = 0; ni < 4; ni++)
                    acc[mi][ni] = MFMA(a[mi], b[ni], acc[mi][ni]);
        }
    }

    __syncthreads();
    float* sPart = (float*)sA;           // [4 wn][128 row][2]

    #pragma unroll
    for (int ni = 0; ni < 4; ni++) {
        int col = wn * 64 + ni * 16 + lr;
        float bv = HASB ? bias[col] : 0.0f;
        #pragma unroll
        for (int mi = 0; mi < 4; mi++)
            #pragma unroll
            for (int j = 0; j < 4; j++) {
                int rowG = brow + wm * 64 + mi * 16 + q * 4 + j;
                acc[mi][ni][j] += bv + h[(size_t)rowG * 256 + col];
            }
    }
    #pragma unroll
    for (int mi = 0; mi < 4; mi++)
        #pragma unroll
        for (int j = 0; j < 4; j++) {
            float s1 = 0.0f, s2 = 0.0f;
            #pragma unroll
            for (int ni = 0; ni < 4; ni++) {
                float v = acc[mi][ni][j];
                s1 += v; s2 += v * v;
            }
            s1 += __shfl_xor(s1, 1); s2 += __shfl_xor(s2, 1);
            s1 += __shfl_xor(s1, 2); s2 += __shfl_xor(s2, 2);
            s1 += __shfl_xor(s1, 4); s2 += __shfl_xor(s2, 4);
            s1 += __shfl_xor(s1, 8); s2 += __shfl_xor(s2, 8);
            if (lr == 0) {
                int lrow = wm * 64 + mi * 16 + q * 4 + j;
                sPart[(wn * 128 + lrow) * 2 + 0] = s1;
                sPart[(wn * 128 + lrow) * 2 + 1] = s2;
            }
        }
    __syncthreads();

    #pragma unroll
    for (int mi = 0; mi < 4; mi++)
        #pragma unroll
        for (int j = 0; j < 4; j++) {
            int lrow = wm * 64 + mi * 16 + q * 4 + j;
            float s1 = sPart[lrow * 2] + sPart[(128 + lrow) * 2] +
                       sPart[(256 + lrow) * 2] + sPart[(384 + lrow) * 2];
            float s2 = sPart[lrow * 2 + 1] + sPart[(128 + lrow) * 2 + 1] +
                       sPart[(256 + lrow) * 2 + 1] + sPart[(384 + lrow) * 2 + 1];
            float mean = s1 * (1.0f / 256.0f);
            float var  = s2 * (1.0f / 256.0f) - mean * mean;
            float rstd = rsqrtf(var + 1e-5f);
            int rowG = brow + lrow;
            #pragma unroll
            for (int ni = 0; ni < 4; ni++) {
                int col = wn * 64 + ni * 16 + lr;
                float v = (acc[mi][ni][j] - mean) * rstd;
                size_t o = (size_t)rowG * 256 + col;
                h[o] = v; hb[o] = f2bf(v);
            }
        }
}

// ------- attention core: S=QK^T, softmax(in-reg), PV -> aob -------
// 64 q-rows/block, 8 waves, XCD-bijective swizzle. Register-prefetch
// software pipeline in both MFMA loops (K split into 3+2 fragment groups;
// V 1-deep double buffer).
__global__ __launch_bounds__(512) void attn_core(
    const u16* __restrict__ qb, const u16* __restrict__ kb,
    const u16* __restrict__ vt, const float* __restrict__ obs,
    u16* __restrict__ aob)
{
    __shared__ __align__(16) u16 sP[64][328];   // 41,984 B
    __shared__ float sBias[320];
    __shared__ float sPm[4][64], sPs[4][64];

    int id = blockIdx.x;                 // 1280 blocks
    int xcd = id & 7, jj = id >> 3;
    int tile = jj % 5, bgrp = jj / 5;
    int b = xcd + 8 * bgrp;
    int t0 = tile * 64;

    int tid = threadIdx.x, w = tid >> 6, lane = tid & 63;
    int mh = w >> 2, jq = w & 3;
    int lr = lane & 15, q = lane >> 4, lk = q * 8;

    if (tid < 320) {
        float msk = (tid < GG) ? obs[((size_t)b * GG + tid) * 9 + 8] : 0.0f;
        sBias[tid] = (1.0f - msk) * -1e9f;
    }
    __syncthreads();

    const u16* qbase = qb + ((size_t)(b * GP + t0 + mh * 32)) * 256;
    const u16* kbase = kb + ((size_t)b * GP) * 256;

    // scores: rows [mh*32,+32) x j in [jq*80,+80), software-pipelined
    f32x4 sacc[2][5];
    #pragma unroll
    for (int mi = 0; mi < 2; mi++)
        #pragma unroll
        for (int jt = 0; jt < 5; jt++) sacc[mi][jt] = {0.0f, 0.0f, 0.0f, 0.0f};

    bf16x8 bA[3], bB[2];
    #pragma unroll
    for (int jt = 0; jt < 3; jt++)
        bA[jt] = *(const bf16x8*)(kbase + ((size_t)(jq * 80 + jt * 16 + lr)) * 256 + lk);

    #pragma unroll
    for (int k = 0; k < 8; k++) {
        bf16x8 a0 = *(const bf16x8*)(qbase + (size_t)lr * 256 + k * 32 + lk);
        bf16x8 a1 = *(const bf16x8*)(qbase + (size_t)(16 + lr) * 256 + k * 32 + lk);
        #pragma unroll
        for (int jt = 3; jt < 5; jt++)
            bB[jt - 3] = *(const bf16x8*)(kbase + ((size_t)(jq * 80 + jt * 16 + lr)) * 256 + k * 32 + lk);
        #pragma unroll
        for (int jt = 0; jt < 3; jt++) {
            sacc[0][jt] = MFMA(a0, bA[jt], sacc[0][jt]);
            sacc[1][jt] = MFMA(a1, bA[jt], sacc[1][jt]);
        }
        if (k < 7) {
            #pragma unroll
            for (int jt = 0; jt < 3; jt++)
                bA[jt] = *(const bf16x8*)(kbase + ((size_t)(jq * 80 + jt * 16 + lr)) * 256 + (k + 1) * 32 + lk);
        }
        #pragma unroll
        for (int jt = 3; jt < 5; jt++) {
            sacc[0][jt] = MFMA(a0, bB[jt - 3], sacc[0][jt]);
            sacc[1][jt] = MFMA(a1, bB[jt - 3], sacc[1][jt]);
        }
    }

    #pragma unroll
    for (int jt = 0; jt < 5; jt++) {
        float bia = sBias[jq * 80 + jt * 16 + lr];
        #pragma unroll
        for (int mi = 0; mi < 2; mi++)
            #pragma unroll
            for (int r = 0; r < 4; r++)
                sacc[mi][jt][r] = sacc[mi][jt][r] * 0.0625f + bia;
    }
    #pragma unroll
    for (int mi = 0; mi < 2; mi++)
        #pragma unroll
        for (int r = 0; r < 4; r++) {
            float mx = -1e30f;
            #pragma unroll
            for (int jt = 0; jt < 5; jt++) mx = fmaxf(mx, sacc[mi][jt][r]);
            mx = fmaxf(mx, __shfl_xor(mx, 1));
            mx = fmaxf(mx, __shfl_xor(mx, 2));
            mx = fmaxf(mx, __shfl_xor(mx, 4));
            mx = fmaxf(mx, __shfl_xor(mx, 8));
            if (lr == 0) sPm[jq][mh * 32 + mi * 16 + q * 4 + r] = mx;
        }
    __syncthreads();
    #pragma unroll
    for (int mi = 0; mi < 2; mi++)
        #pragma unroll
        for (int r = 0; r < 4; r++) {
            int row = mh * 32 + mi * 16 + q * 4 + r;
            float rm = fmaxf(fmaxf(sPm[0][row], sPm[1][row]), fmaxf(sPm[2][row], sPm[3][row]));
            float ss = 0.0f;
            #pragma unroll
            for (int jt = 0; jt < 5; jt++) {
                float e = __expf(sacc[mi][jt][r] - rm);
                sacc[mi][jt][r] = e;
                ss += e;
            }
            ss += __shfl_xor(ss, 1);
            ss += __shfl_xor(ss, 2);
            ss += __shfl_xor(ss, 4);
            ss += __shfl_xor(ss, 8);
            if (lr == 0) sPs[jq][row] = ss;
        }
    __syncthreads();
    #pragma unroll
    for (int mi = 0; mi < 2; mi++)
        #pragma unroll
        for (int r = 0; r < 4; r++) {
            int row = mh * 32 + mi * 16 + q * 4 + r;
            float inv = 1.0f / (sPs[0][row] + sPs[1][row] + sPs[2][row] + sPs[3][row]);
            #pragma unroll
            for (int jt = 0; jt < 5; jt++)
                sP[row][jq * 80 + jt * 16 + lr] = f2bf(sacc[mi][jt][r] * inv);
        }
    __syncthreads();

    // PV: rows [mh*32,+32) x e in [jq*64,+64), 1-deep V prefetch
    const u16* vbase = vt + (size_t)b * EE * GP;
    f32x4 oacc[2][4];
    #pragma unroll
    for (int mi = 0; mi < 2; mi++)
        #pragma unroll
        for (int ni = 0; ni < 4; ni++) oacc[mi][ni] = {0.0f, 0.0f, 0.0f, 0.0f};

    bf16x8 vc[4], vn[4];
    #pragma unroll
    for (int ni = 0; ni < 4; ni++)
        vc[ni] = *(const bf16x8*)(vbase + ((size_t)(jq * 64 + ni * 16 + lr)) * GP + lk);

    #pragma unroll
    for (int ks = 0; ks < 10; ks++) {
        if (ks < 9) {
            #pragma unroll
            for (int ni = 0; ni < 4; ni++)
                vn[ni] = *(const bf16x8*)(vbase + ((size_t)(jq * 64 + ni * 16 + lr)) * GP + (ks + 1) * 32 + lk);
        }
        bf16x8 a0 = *(const bf16x8*)(&sP[mh * 32 + lr][ks * 32 + lk]);
        bf16x8 a1 = *(const bf16x8*)(&sP[mh * 32 + 16 + lr][ks * 32 + lk]);
        #pragma unroll
        for (int ni = 0; ni < 4; ni++) {
            oacc[0][ni] = MFMA(a0, vc[ni], oacc[0][ni]);
            oacc[1][ni] = MFMA(a1, vc[ni], oacc[1][ni]);
        }
        #pragma unroll
        for (int ni = 0; ni < 4; ni++) vc[ni] = vn[ni];
    }
    #pragma unroll
    for (int mi = 0; mi < 2; mi++)
        #pragma unroll
        for (int ni = 0; ni < 4; ni++) {
            int col = jq * 64 + ni * 16 + lr;
            #pragma unroll
            for (int r = 0; r < 4; r++) {
                int row = mh * 32 + mi * 16 + q * 4 + r;
                aob[((size_t)(b * GP + t0 + row)) * 256 + col] = f2bf(oacc[mi][ni][r]);
            }
        }
}

// ------------- head part 1: graph embed -> fixed context -> u[b] -------------
__global__ __launch_bounds__(256) void final1_kernel(
    const float* __restrict__ h, const float* __restrict__ obs,
    const float* __restrict__ w_fc, const float* __restrict__ w_pn,
    float* __restrict__ u)
{
    int b = blockIdx.x;
    int t = threadIdx.x;
    __shared__ float ges[EE];
    __shared__ float fcs[EE];

    float acc = 0.0f, vlen = 0.0f;
    for (int g = 0; g < GG; g++) {
        float m = obs[((size_t)b * GG + g) * 9 + 8];
        vlen += m;
        acc += h[((size_t)b * GP + g) * EE + t] * m;
    }
    ges[t] = acc / vlen;
    __syncthreads();

    float fc = 0.0f;
    for (int kk = 0; kk < EE; kk++) fc += ges[kk] * w_fc[kk * EE + t];
    fcs[t] = fc;
    __syncthreads();

    const float4* wp = reinterpret_cast<const float4*>(w_pn + (size_t)t * 3 * EE);
    float ua = 0.0f;
    for (int kk = 0; kk < EE / 4; kk++) {
        float4 w = wp[kk];
        ua += w.x * fcs[kk * 4] + w.y * fcs[kk * 4 + 1] +
              w.z * fcs[kk * 4 + 2] + w.w * fcs[kk * 4 + 3];
    }
    u[(size_t)b * EE + t] = ua;
}

// ------------- head part 2: compat -> tanh clip -> masked softmax -------------
__global__ __launch_bounds__(128) void final2_kernel(
    const float* __restrict__ h, const float* __restrict__ obs,
    const float* __restrict__ u, float* __restrict__ out)
{
    int b = blockIdx.x;
    int t = threadIdx.x;
    __shared__ float us[EE];
    __shared__ float red[8];
    us[t]       = u[(size_t)b * EE + t];
    us[t + 128] = u[(size_t)b * EE + t + 128];
    __syncthreads();

    float logit = -INFINITY;
    float m = 0.0f;
    if (t < LHN) {
        int g = IHN + t;
        m = obs[((size_t)b * GG + g) * 9 + 8];
        const float4* hr = reinterpret_cast<const float4*>(h + ((size_t)b * GP + g) * EE);
        float c = 0.0f;
        for (int kk = 0; kk < EE / 4; kk++) {
            float4 hv = hr[kk];
            c += hv.x * us[kk * 4] + hv.y * us[kk * 4 + 1] +
                 hv.z * us[kk * 4 + 2] + hv.w * us[kk * 4 + 3];
        }
        c *= m;
        c *= 0.0625f;
        logit = tanhf(c) * 10.0f;
    }
    float bm = blockReduceMax(logit, red);
    float e  = (t < LHN) ? __expf(logit - bm) : 0.0f;
    float bs = blockReduceSum(e, red);
    float p  = e / bs;
    float masked = (t < LHN) ? (p * m + 1e-20f) : 0.0f;
    float bs2 = blockReduceSum(masked, red);
    if (t < LHN) out[(size_t)b * LHN + t] = masked / bs2;
}

extern "C" void kernel_launch(void* const* d_in, const int* in_sizes, int n_in,
                              void* d_out, int out_size, void* d_ws, size_t ws_size,
                              hipStream_t stream) {
    const float* obs   = (const float*)d_in[0];
    const float* wi1   = (const float*)d_in[1];
    const float* bi1   = (const float*)d_in[2];
    const float* wi2   = (const float*)d_in[3];
    const float* bi2   = (const float*)d_in[4];
    const float* wl1   = (const float*)d_in[5];
    const float* bl1   = (const float*)d_in[6];
    const float* wl2   = (const float*)d_in[7];
    const float* bl2   = (const float*)d_in[8];
    const float* wn1   = (const float*)d_in[9];
    const float* bn1   = (const float*)d_in[10];
    const float* wn2   = (const float*)d_in[11];
    const float* bn2   = (const float*)d_in[12];
    const float* e_wq  = (const float*)d_in[13];
    const float* e_wk  = (const float*)d_in[14];
    const float* e_wv  = (const float*)d_in[15];
    const float* e_wo  = (const float*)d_in[16];
    const float* e_wf1 = (const float*)d_in[17];
    const float* e_bf1 = (const float*)d_in[18];
    const float* e_wf2 = (const float*)d_in[19];
    const float* e_bf2 = (const float*)d_in[20];
    const float* w_pn  = (const float*)d_in[21];
    const float* w_fc  = (const float*)d_in[22];
    float* outp = (float*)d_out;

    // ---- compact workspace layout: 254,017,536 B total ----
    char* wsc = (char*)d_ws;
    float* h    = (float*)wsc;
    u16*   hb   = (u16*)(wsc + 83886080);
    u16*   qaob = (u16*)(wsc + 125829120);   // qb, later aob
    u16*   kb   = (u16*)(wsc + 167772160);
    u16*   vt   = (u16*)(wsc + 209715200);
    u16*   wT   = (u16*)(wsc + 251658240);
    float* ubuf = (float*)(wsc + 253755392);
    u16*   hidb = kb;  // overlays kb+vt (disjoint lifetime)

    prep_kernel<<<dim3(512, 12), 256, 0, stream>>>(e_wq, e_wk, e_wv, e_wo, e_wf1, e_wf2, wT);
    pad_kernel<<<BB, 256, 0, stream>>>(h, hb);
    embed_seg<ILN, IHN, 0><<<IHN * BB / 32, 256, 0, stream>>>(obs, wi1, bi1, wi2, bi2, h, hb);
    embed_seg<8, LHN, IHN><<<LHN * BB / 32, 256, 0, stream>>>(obs, wl1, bl1, wl2, bl2, h, hb);
    embed_seg<6, 1, IHN + LHN><<<BB / 32, 256, 0, stream>>>(obs, wn1, bn1, wn2, bn2, h, hb);

    const size_t WL = 524288;
    for (int l = 0; l < NL; l++) {
        u16* wqkvT = wT + l * WL;
        u16* woT   = wqkvT + 196608;
        u16* w1T   = wqkvT + 262144;
        u16* w2T   = wqkvT + 393216;
        const float* bf1 = e_bf1 + (size_t)l * FFH;
        const float* bf2 = e_bf2 + (size_t)l * EE;

        qkv_gemm<<<dim3(MT / 128, 6), 256, 0, stream>>>(hb, wqkvT, qaob, kb, vt);
        attn_core<<<1280, 512, 0, stream>>>(qaob, kb, vt, obs, qaob);
        gemmln_kernel<4, 256, 256, false><<<MT / 128, 512, 0, stream>>>(qaob, woT, nullptr, h, hb);
        ff1_gemm<<<dim3(MT / 128, 4), 256, 0, stream>>>(hb, w1T, bf1, hidb);
        gemmln_kernel<8, 512, 512, true><<<MT / 128, 512, 0, stream>>>(hidb, w2T, bf2, h, hb);
    }
    final1_kernel<<<BB, 256, 0, stream>>>(h, obs, w_fc, w_pn, ubuf);
    final2_kernel<<<BB, 128, 0, stream>>>(h, obs, ubuf, outp);
}